// Round 8
// baseline (2485.399 us; speedup 1.0000x reference)
//
#include <hip/hip_runtime.h>
#include <cfloat>
#include <cmath>

#define D 128
#define D4 32   // D/4 float4s per row
#define D8 32   // D/4 ushort4s per bf16 row
#define TN 32   // dst-nodes per gather block

// ---------- helpers ----------
__device__ __forceinline__ float4 f4fma(float s, float4 a, float4 acc) {
    acc.x = fmaf(s, a.x, acc.x);
    acc.y = fmaf(s, a.y, acc.y);
    acc.z = fmaf(s, a.z, acc.z);
    acc.w = fmaf(s, a.w, acc.w);
    return acc;
}

__device__ __forceinline__ unsigned short f2bf(float x) {
    unsigned int b = __float_as_uint(x);
    unsigned int r = (b + 0x7FFFu + ((b >> 16) & 1u)) >> 16;   // RNE
    return (unsigned short)r;
}

__device__ __forceinline__ float bf2f(unsigned short u) {
    return __uint_as_float(((unsigned int)u) << 16);
}

// ---------- degree count (int) ----------
__global__ void k_count(const int* __restrict__ dst, int* __restrict__ cnt, int E) {
    int i = blockIdx.x * blockDim.x + threadIdx.x;
    if (i < E) atomicAdd(&cnt[dst[i]], 1);
}

__global__ void k_dinv(const int* __restrict__ cnt, float* __restrict__ dinv, int N) {
    int i = blockIdx.x * blockDim.x + threadIdx.x;
    if (i < N) dinv[i] = 1.0f / sqrtf((float)cnt[i] + 1.0f);  // +1 = self-loop
}

// ---------- exclusive scan of cnt -> rowptr (single block, 1024 thr) ----------
__global__ __launch_bounds__(1024)
void k_scan(const int* __restrict__ cnt, int* __restrict__ rowptr,
            int* __restrict__ cur, int N) {
    __shared__ int part[1024];
    int t = threadIdx.x;
    int chunk = (N + 1023) / 1024;
    int begin = t * chunk;
    int end = begin + chunk; if (end > N) end = N;
    int s = 0;
    for (int i = begin; i < end; ++i) s += cnt[i];
    part[t] = s;
    __syncthreads();
    for (int off = 1; off < 1024; off <<= 1) {
        int v = (t >= off) ? part[t - off] : 0;
        __syncthreads();
        part[t] += v;
        __syncthreads();
    }
    int run = (t == 0) ? 0 : part[t - 1];
    for (int i = begin; i < end; ++i) {
        rowptr[i] = run; cur[i] = run;
        run += cnt[i];
    }
    if (t == 1023) rowptr[N] = part[1023];
}

// ---------- fill CSR edge data: (src, norm), dst — sorted by dst ----------
__global__ void k_fill(const int* __restrict__ src, const int* __restrict__ dst,
                       const float* __restrict__ dinv, int* __restrict__ cur,
                       int2* __restrict__ edata, int* __restrict__ edst, int E) {
    int e = blockIdx.x * blockDim.x + threadIdx.x;
    if (e >= E) return;
    int s = src[e], d = dst[e];
    int p = atomicAdd(&cur[d], 1);
    edata[p] = make_int2(s, __float_as_int(dinv[s] * dinv[d]));
    edst[p] = d;
}

// ---------- encoder: h = elu(x @ enc_w + enc_b), x:[N,3] ----------
__global__ void k_enc(const float* __restrict__ x, const float* __restrict__ w,
                      const float* __restrict__ b, float* __restrict__ h, int N) {
    int idx = blockIdx.x * blockDim.x + threadIdx.x;   // over N*D4
    if (idx >= N * D4) return;
    int n = idx >> 5, c4 = idx & 31;
    const float4* w4 = (const float4*)w;
    float4 b4 = ((const float4*)b)[c4];
    float x0 = x[n * 3 + 0], x1 = x[n * 3 + 1], x2 = x[n * 3 + 2];
    float4 v = b4;
    v = f4fma(x0, w4[0 * D4 + c4], v);
    v = f4fma(x1, w4[1 * D4 + c4], v);
    v = f4fma(x2, w4[2 * D4 + c4], v);
    v.x = v.x > 0.f ? v.x : expm1f(v.x);
    v.y = v.y > 0.f ? v.y : expm1f(v.y);
    v.z = v.z > 0.f ? v.z : expm1f(v.z);
    v.w = v.w > 0.f ? v.w : expm1f(v.w);
    ((float4*)h)[idx] = v;
}

// ---------- per-layer LN-fold: W' = s_c * W, konst_j = sum_c o_c * W_cj ----------
__global__ void k_prep(const float* __restrict__ w, const float* __restrict__ lw,
                       const float* __restrict__ lb, const double* __restrict__ sums,
                       float* __restrict__ wout, float* __restrict__ konst, int N) {
    __shared__ float sc[D], of[D];
    float mu = 0.f, inv = 1.f;
    if (lw) {
        double M = (double)N * D;
        double m = sums[0] / M;
        double var = sums[1] / M - m * m;
        float sd = sqrtf(var > 0.0 ? (float)var : 0.f);
        inv = 1.f / (sd + 1e-5f);
        mu = (float)m;
    }
    for (int i = threadIdx.x; i < D; i += blockDim.x) {
        float l = lw ? lw[i] : 1.f;
        float s = inv * l;
        sc[i] = s;
        of[i] = (lw ? lb[i] : 0.f) - mu * s;
    }
    __syncthreads();
    if (blockIdx.x < 8) {
        int chunk = D * D / 8;   // 2048
        int base = blockIdx.x * chunk;
        for (int i = threadIdx.x; i < chunk; i += blockDim.x) {
            int idx = base + i;
            wout[idx] = sc[idx >> 7] * w[idx];
        }
    } else {
        for (int j = threadIdx.x; j < D; j += blockDim.x) {
            float acc = 0.f;
            for (int c = 0; c < D; ++c) acc = fmaf(of[c], w[c * D + j], acc);
            konst[j] = acc;
        }
    }
}

// ---------- dense matmul: T[N,128](bf16) = h[N,128] @ wp[128,128] + konst ----
__launch_bounds__(256)
__global__ void k_mm(const float* __restrict__ h, const float* __restrict__ wp,
                     const float* __restrict__ konst, unsigned short* __restrict__ out,
                     int N) {
    __shared__ float wl[D * D];          // 64 KB
    float4* wl4 = (float4*)wl;
    const float4* wg4 = (const float4*)wp;
    for (int i = threadIdx.x; i < D * D4; i += 256) wl4[i] = wg4[i];
    __syncthreads();

    int cg = threadIdx.x & 31;
    int rg = threadIdx.x >> 5;
    int row0 = blockIdx.x * 64 + rg * 8;
    const float4* h4 = (const float4*)h;
    float4 k4 = ((const float4*)konst)[cg];

    float4 acc[8];
    #pragma unroll
    for (int r = 0; r < 8; ++r) acc[r] = k4;

    int nodes[8];
    #pragma unroll
    for (int r = 0; r < 8; ++r) { int nd = row0 + r; nodes[r] = nd < N ? nd : N - 1; }

    for (int kk = 0; kk < D; kk += 4) {
        float4 w0 = wl4[(kk + 0) * D4 + cg];
        float4 w1 = wl4[(kk + 1) * D4 + cg];
        float4 w2 = wl4[(kk + 2) * D4 + cg];
        float4 w3 = wl4[(kk + 3) * D4 + cg];
        #pragma unroll
        for (int r = 0; r < 8; ++r) {
            float4 hv = h4[(size_t)nodes[r] * D4 + (kk >> 2)];
            acc[r] = f4fma(hv.x, w0, acc[r]);
            acc[r] = f4fma(hv.y, w1, acc[r]);
            acc[r] = f4fma(hv.z, w2, acc[r]);
            acc[r] = f4fma(hv.w, w3, acc[r]);
        }
    }
    #pragma unroll
    for (int r = 0; r < 8; ++r) {
        int nd = row0 + r;
        if (nd < N) {
            ushort4 o;
            o.x = f2bf(acc[r].x); o.y = f2bf(acc[r].y);
            o.z = f2bf(acc[r].z); o.w = f2bf(acc[r].w);
            ((ushort4*)out)[(size_t)nd * D8 + cg] = o;
        }
    }
}

// ---------- edge-parallel gather into LDS + self-loop + bias + relu + LN stats
// Block owns TN=32 dst nodes; edges [rowptr[n0], rowptr[n0+32]) processed
// edge-parallel: wave w takes e = e_lo+w, stride 4, 8-deep unroll. Each edge:
// full wave loads the 256B bf16 row of src (lane = 2 channels), scales, LDS-adds.
__launch_bounds__(256)
__global__ void k_gather(const unsigned short* __restrict__ T,
                         const int2* __restrict__ edata, const int* __restrict__ edst,
                         const int* __restrict__ rowptr, const float* __restrict__ dinv,
                         const float* __restrict__ bias, float* __restrict__ outA,
                         double* __restrict__ sums, int N) {
    __shared__ float lacc[TN][D];        // 16 KB
    const unsigned int* T2 = (const unsigned int*)T;

    int n0 = blockIdx.x * TN;
    int nEnd = n0 + TN < N ? n0 + TN : N;
    int e_lo = rowptr[n0], e_hi = rowptr[nEnd];

    // zero accumulators
    for (int i = threadIdx.x; i < TN * D / 4; i += 256)
        ((float4*)lacc)[i] = make_float4(0.f, 0.f, 0.f, 0.f);
    __syncthreads();

    int wv = threadIdx.x >> 6;           // wave 0..3
    int lane = threadIdx.x & 63;         // channels 2*lane, 2*lane+1

    int e = e_lo + wv;
    // 8-edge batches (per wave, stride 4)
    for (; e + 28 < e_hi; e += 32) {
        int2 ed[8]; int dn[8]; unsigned int tv[8];
        #pragma unroll
        for (int j = 0; j < 8; ++j) ed[j] = edata[e + 4 * j];
        #pragma unroll
        for (int j = 0; j < 8; ++j) dn[j] = edst[e + 4 * j];
        #pragma unroll
        for (int j = 0; j < 8; ++j) tv[j] = T2[(size_t)ed[j].x * 64 + lane];
        #pragma unroll
        for (int j = 0; j < 8; ++j) {
            float nrm = __int_as_float(ed[j].y);
            float lo = bf2f((unsigned short)(tv[j] & 0xFFFFu));
            float hi = bf2f((unsigned short)(tv[j] >> 16));
            int nl = dn[j] - n0;
            atomicAdd(&lacc[nl][2 * lane + 0], nrm * lo);
            atomicAdd(&lacc[nl][2 * lane + 1], nrm * hi);
        }
    }
    // remainder
    for (; e < e_hi; e += 4) {
        int2 ed = edata[e];
        int nl = edst[e] - n0;
        unsigned int tv = T2[(size_t)ed.x * 64 + lane];
        float nrm = __int_as_float(ed.y);
        atomicAdd(&lacc[nl][2 * lane + 0], nrm * bf2f((unsigned short)(tv & 0xFFFFu)));
        atomicAdd(&lacc[nl][2 * lane + 1], nrm * bf2f((unsigned short)(tv >> 16)));
    }
    __syncthreads();

    // epilogue: self-loop + bias + relu, write A, LN stats
    int c2 = threadIdx.x & 63;           // channel pair
    int no = threadIdx.x >> 6;           // node offset 0..3
    float2 b2 = ((const float2*)bias)[c2];
    float ls = 0.f, lq = 0.f;
    #pragma unroll
    for (int k = 0; k < TN / 4; ++k) {
        int nl = no + 4 * k;
        int n = n0 + nl;
        if (n < N) {
            unsigned int tv = T2[(size_t)n * 64 + c2];
            float di = dinv[n];
            float sl = di * di;
            float v0 = lacc[nl][2 * c2 + 0] + sl * bf2f((unsigned short)(tv & 0xFFFFu)) + b2.x;
            float v1 = lacc[nl][2 * c2 + 1] + sl * bf2f((unsigned short)(tv >> 16)) + b2.y;
            v0 = fmaxf(v0, 0.f); v1 = fmaxf(v1, 0.f);
            ((float2*)outA)[(size_t)n * 64 + c2] = make_float2(v0, v1);
            ls += v0 + v1;
            lq += v0 * v0 + v1 * v1;
        }
    }
    // wave64 reduce
    for (int off = 32; off; off >>= 1) {
        ls += __shfl_down(ls, off);
        lq += __shfl_down(lq, off);
    }
    __shared__ float ss[4], sq[4];
    if ((threadIdx.x & 63) == 0) { ss[wv] = ls; sq[wv] = lq; }
    __syncthreads();
    if (threadIdx.x == 0) {
        float S = ss[0] + ss[1] + ss[2] + ss[3];
        float Q = sq[0] + sq[1] + sq[2] + sq[3];
        atomicAdd(&sums[0], (double)S);
        atomicAdd(&sums[1], (double)Q);
    }
}

// ---------- global max pool per graph, applying final LN inline ----------
__launch_bounds__(512)
__global__ void k_pool(const float* __restrict__ A, const int* __restrict__ batch,
                       const float* __restrict__ lw, const float* __restrict__ lb,
                       const double* __restrict__ sums, float* __restrict__ g, int N) {
    int gi = blockIdx.x;
    int lo = 0, hi = N;
    while (lo < hi) { int mid = (lo + hi) >> 1; if (batch[mid] < gi) lo = mid + 1; else hi = mid; }
    int start = lo;
    hi = N;
    while (lo < hi) { int mid = (lo + hi) >> 1; if (batch[mid] < gi + 1) lo = mid + 1; else hi = mid; }
    int end = lo;

    int c = threadIdx.x & 127, sub = threadIdx.x >> 7;
    double M = (double)N * D;
    double m_ = sums[0] / M;
    double var = sums[1] / M - m_ * m_;
    float sd = sqrtf(var > 0.0 ? (float)var : 0.f);
    float inv = 1.f / (sd + 1e-5f);
    float s = inv * lw[c];
    float o = lb[c] - (float)m_ * s;

    float mx = -FLT_MAX;
    for (int node = start + sub; node < end; node += 4)
        mx = fmaxf(mx, fmaf(A[(size_t)node * D + c], s, o));

    __shared__ float red[4][128];
    red[sub][c] = mx;
    __syncthreads();
    if (sub == 0) {
        mx = fmaxf(fmaxf(red[0][c], red[1][c]), fmaxf(red[2][c], red[3][c]));
        g[gi * D + c] = mx;
    }
}

// ---------- t = tanh(g @ fc_w + fc_b) ----------
__global__ void k_fc(const float* __restrict__ g, const float* __restrict__ w,
                     const float* __restrict__ b, float* __restrict__ t) {
    __shared__ float row[D];
    int gi = blockIdx.x, c = threadIdx.x;
    row[c] = g[gi * D + c];
    __syncthreads();
    float acc = b[c];
    for (int k = 0; k < D; ++k) acc = fmaf(row[k], w[k * D + c], acc);
    t[gi * D + c] = tanhf(acc);
}

// ---------- out = t @ pred_w + pred_b ----------
__global__ void k_pred(const float* __restrict__ t, const float* __restrict__ w,
                       const float* __restrict__ b, float* __restrict__ out, int total) {
    int i = blockIdx.x * blockDim.x + threadIdx.x;
    if (i >= total) return;
    int gi = i / 10, j = i % 10;
    float acc = b[j];
    for (int k = 0; k < D; ++k) acc = fmaf(t[gi * D + k], w[k * 10 + j], acc);
    out[i] = acc;
}

extern "C" void kernel_launch(void* const* d_in, const int* in_sizes, int n_in,
                              void* d_out, int out_size, void* d_ws, size_t ws_size,
                              hipStream_t stream) {
    const float* x      = (const float*)d_in[0];
    const int*   src    = (const int*)d_in[1];
    const int*   dst    = (const int*)d_in[2];
    const int*   batch  = (const int*)d_in[3];
    const float* enc_w  = (const float*)d_in[4];
    const float* enc_b  = (const float*)d_in[5];
    const float* fc_w   = (const float*)d_in[6];
    const float* fc_b   = (const float*)d_in[7];
    const float* pred_w = (const float*)d_in[8];
    const float* pred_b = (const float*)d_in[9];

    int N = in_sizes[0] / 3;
    int E = in_sizes[1];
    int G = out_size / 10;

    char* ws = (char*)d_ws;
    size_t off = 0;
    auto align512 = [](size_t v) { return (v + 511) / 512 * 512; };
    float* dinv   = (float*)(ws + off); off += align512((size_t)N * 4);
    int*   cnt    = (int*)(ws + off);   off += align512((size_t)N * 4);
    int*   rowptr = (int*)(ws + off);   off += align512(((size_t)N + 1) * 4);
    int*   cur    = (int*)(ws + off);   off += align512((size_t)N * 4);
    int2*  edata  = (int2*)(ws + off);  off += align512((size_t)E * 8);
    int*   edst   = (int*)(ws + off);   off += align512((size_t)E * 4);
    float* A      = (float*)(ws + off); off += (size_t)N * D * 4;
    unsigned short* T = (unsigned short*)(ws + off); off += align512((size_t)N * D * 2);
    double* sums  = (double*)(ws + off); off += 512;
    float* wp     = (float*)(ws + off); off += (size_t)D * D * 4;
    float* konst  = (float*)(ws + off); off += align512((size_t)D * 4);
    float* gmax   = (float*)(ws + off); off += (size_t)G * D * 4;
    float* tb     = (float*)(ws + off); off += (size_t)G * D * 4;

    // ---- CSR build (per launch; inputs restored every call) ----
    hipMemsetAsync(cnt, 0, (size_t)N * 4, stream);
    k_count<<<(E + 255) / 256, 256, 0, stream>>>(dst, cnt, E);
    k_dinv<<<(N + 255) / 256, 256, 0, stream>>>(cnt, dinv, N);
    k_scan<<<1, 1024, 0, stream>>>(cnt, rowptr, cur, N);
    k_fill<<<(E + 255) / 256, 256, 0, stream>>>(src, dst, dinv, cur, edata, edst, E);

    // ---- encoder ----
    int tot4 = N * D4;
    k_enc<<<(tot4 + 255) / 256, 256, 0, stream>>>(x, enc_w, enc_b, A, N);

    // ---- 4 GCN layers (LN of layer L-1 folded into layer L's weights) ----
    for (int L = 0; L < 4; ++L) {
        const float* w  = (const float*)d_in[10 + 4 * L];
        const float* b  = (const float*)d_in[11 + 4 * L];
        const float* lwp = L ? (const float*)d_in[12 + 4 * (L - 1)] : nullptr;
        const float* lbp = L ? (const float*)d_in[13 + 4 * (L - 1)] : nullptr;
        k_prep<<<9, 256, 0, stream>>>(w, lwp, lbp, sums, wp, konst, N);
        k_mm<<<(N + 63) / 64, 256, 0, stream>>>(A, wp, konst, T, N);
        hipMemsetAsync(sums, 0, 16, stream);
        k_gather<<<(N + TN - 1) / TN, 256, 0, stream>>>(T, edata, edst, rowptr, dinv, b, A, sums, N);
    }

    // ---- final LN applied inside pool ----
    const float* lw3 = (const float*)d_in[12 + 4 * 3];
    const float* lb3 = (const float*)d_in[13 + 4 * 3];
    k_pool<<<G, 512, 0, stream>>>(A, batch, lw3, lb3, sums, gmax, N);
    k_fc<<<G, D, 0, stream>>>(gmax, fc_w, fc_b, tb);
    k_pred<<<(G * 10 + 255) / 256, 256, 0, stream>>>(tb, pred_w, pred_b, (float*)d_out, G * 10);
}

// Round 9
// 903.214 us; speedup vs baseline: 2.7517x; 2.7517x over previous
//
#include <hip/hip_runtime.h>
#include <cfloat>
#include <cmath>

#define D 128
#define D4 32   // D/4 float4s per f32 row
#define D8 32   // D/4 ushort4s per bf16 row

// ---------- helpers ----------
__device__ __forceinline__ float4 f4fma(float s, float4 a, float4 acc) {
    acc.x = fmaf(s, a.x, acc.x);
    acc.y = fmaf(s, a.y, acc.y);
    acc.z = fmaf(s, a.z, acc.z);
    acc.w = fmaf(s, a.w, acc.w);
    return acc;
}

__device__ __forceinline__ unsigned short f2bf(float x) {
    unsigned int b = __float_as_uint(x);
    unsigned int r = (b + 0x7FFFu + ((b >> 16) & 1u)) >> 16;   // RNE
    return (unsigned short)r;
}

__device__ __forceinline__ float bf2f(unsigned short u) {
    return __uint_as_float(((unsigned int)u) << 16);
}

// accumulate 8 bf16 channels (one uint4) scaled by nrm into acc[8]
__device__ __forceinline__ void accum8(float* a, float nrm, uint4 t) {
    a[0] = fmaf(nrm, bf2f((unsigned short)(t.x & 0xFFFFu)), a[0]);
    a[1] = fmaf(nrm, bf2f((unsigned short)(t.x >> 16)), a[1]);
    a[2] = fmaf(nrm, bf2f((unsigned short)(t.y & 0xFFFFu)), a[2]);
    a[3] = fmaf(nrm, bf2f((unsigned short)(t.y >> 16)), a[3]);
    a[4] = fmaf(nrm, bf2f((unsigned short)(t.z & 0xFFFFu)), a[4]);
    a[5] = fmaf(nrm, bf2f((unsigned short)(t.z >> 16)), a[5]);
    a[6] = fmaf(nrm, bf2f((unsigned short)(t.w & 0xFFFFu)), a[6]);
    a[7] = fmaf(nrm, bf2f((unsigned short)(t.w >> 16)), a[7]);
}

// ---------- degree count (int) ----------
__global__ void k_count(const int* __restrict__ dst, int* __restrict__ cnt, int E) {
    int i = blockIdx.x * blockDim.x + threadIdx.x;
    if (i < E) atomicAdd(&cnt[dst[i]], 1);
}

__global__ void k_dinv(const int* __restrict__ cnt, float* __restrict__ dinv, int N) {
    int i = blockIdx.x * blockDim.x + threadIdx.x;
    if (i < N) dinv[i] = 1.0f / sqrtf((float)cnt[i] + 1.0f);  // +1 = self-loop
}

// ---------- exclusive scan of cnt -> rowptr (single block, 1024 thr) ----------
__global__ __launch_bounds__(1024)
void k_scan(const int* __restrict__ cnt, int* __restrict__ rowptr,
            int* __restrict__ cur, int N) {
    __shared__ int part[1024];
    int t = threadIdx.x;
    int chunk = (N + 1023) / 1024;
    int begin = t * chunk;
    int end = begin + chunk; if (end > N) end = N;
    int s = 0;
    for (int i = begin; i < end; ++i) s += cnt[i];
    part[t] = s;
    __syncthreads();
    for (int off = 1; off < 1024; off <<= 1) {
        int v = (t >= off) ? part[t - off] : 0;
        __syncthreads();
        part[t] += v;
        __syncthreads();
    }
    int run = (t == 0) ? 0 : part[t - 1];
    for (int i = begin; i < end; ++i) {
        rowptr[i] = run; cur[i] = run;
        run += cnt[i];
    }
    if (t == 1023) rowptr[N] = part[1023];
}

// ---------- fill CSR edge data: (src, norm) sorted by dst ----------
__global__ void k_fill(const int* __restrict__ src, const int* __restrict__ dst,
                       const float* __restrict__ dinv, int* __restrict__ cur,
                       int2* __restrict__ edata, int E) {
    int e = blockIdx.x * blockDim.x + threadIdx.x;
    if (e >= E) return;
    int s = src[e], d = dst[e];
    int p = atomicAdd(&cur[d], 1);
    edata[p] = make_int2(s, __float_as_int(dinv[s] * dinv[d]));
}

// ---------- encoder: h = elu(x @ enc_w + enc_b), x:[N,3] ----------
__global__ void k_enc(const float* __restrict__ x, const float* __restrict__ w,
                      const float* __restrict__ b, float* __restrict__ h, int N) {
    int idx = blockIdx.x * blockDim.x + threadIdx.x;   // over N*D4
    if (idx >= N * D4) return;
    int n = idx >> 5, c4 = idx & 31;
    const float4* w4 = (const float4*)w;
    float4 b4 = ((const float4*)b)[c4];
    float x0 = x[n * 3 + 0], x1 = x[n * 3 + 1], x2 = x[n * 3 + 2];
    float4 v = b4;
    v = f4fma(x0, w4[0 * D4 + c4], v);
    v = f4fma(x1, w4[1 * D4 + c4], v);
    v = f4fma(x2, w4[2 * D4 + c4], v);
    v.x = v.x > 0.f ? v.x : expm1f(v.x);
    v.y = v.y > 0.f ? v.y : expm1f(v.y);
    v.z = v.z > 0.f ? v.z : expm1f(v.z);
    v.w = v.w > 0.f ? v.w : expm1f(v.w);
    ((float4*)h)[idx] = v;
}

// ---------- per-layer LN-fold: W' = s_c * W, konst_j = sum_c o_c * W_cj ----------
__global__ void k_prep(const float* __restrict__ w, const float* __restrict__ lw,
                       const float* __restrict__ lb, const double* __restrict__ sums,
                       float* __restrict__ wout, float* __restrict__ konst, int N) {
    __shared__ float sc[D], of[D];
    float mu = 0.f, inv = 1.f;
    if (lw) {
        double M = (double)N * D;
        double m = sums[0] / M;
        double var = sums[1] / M - m * m;
        float sd = sqrtf(var > 0.0 ? (float)var : 0.f);
        inv = 1.f / (sd + 1e-5f);
        mu = (float)m;
    }
    for (int i = threadIdx.x; i < D; i += blockDim.x) {
        float l = lw ? lw[i] : 1.f;
        float s = inv * l;
        sc[i] = s;
        of[i] = (lw ? lb[i] : 0.f) - mu * s;
    }
    __syncthreads();
    if (blockIdx.x < 8) {
        int chunk = D * D / 8;   // 2048
        int base = blockIdx.x * chunk;
        for (int i = threadIdx.x; i < chunk; i += blockDim.x) {
            int idx = base + i;
            wout[idx] = sc[idx >> 7] * w[idx];
        }
    } else {
        for (int j = threadIdx.x; j < D; j += blockDim.x) {
            float acc = 0.f;
            for (int c = 0; c < D; ++c) acc = fmaf(of[c], w[c * D + j], acc);
            konst[j] = acc;
        }
    }
}

// ---------- dense matmul: T[N,128](bf16) = h[N,128] @ wp[128,128] + konst ----
__launch_bounds__(256)
__global__ void k_mm(const float* __restrict__ h, const float* __restrict__ wp,
                     const float* __restrict__ konst, unsigned short* __restrict__ out,
                     int N) {
    __shared__ float wl[D * D];          // 64 KB
    float4* wl4 = (float4*)wl;
    const float4* wg4 = (const float4*)wp;
    for (int i = threadIdx.x; i < D * D4; i += 256) wl4[i] = wg4[i];
    __syncthreads();

    int cg = threadIdx.x & 31;
    int rg = threadIdx.x >> 5;
    int row0 = blockIdx.x * 64 + rg * 8;
    const float4* h4 = (const float4*)h;
    float4 k4 = ((const float4*)konst)[cg];

    float4 acc[8];
    #pragma unroll
    for (int r = 0; r < 8; ++r) acc[r] = k4;

    int nodes[8];
    #pragma unroll
    for (int r = 0; r < 8; ++r) { int nd = row0 + r; nodes[r] = nd < N ? nd : N - 1; }

    for (int kk = 0; kk < D; kk += 4) {
        float4 w0 = wl4[(kk + 0) * D4 + cg];
        float4 w1 = wl4[(kk + 1) * D4 + cg];
        float4 w2 = wl4[(kk + 2) * D4 + cg];
        float4 w3 = wl4[(kk + 3) * D4 + cg];
        #pragma unroll
        for (int r = 0; r < 8; ++r) {
            float4 hv = h4[(size_t)nodes[r] * D4 + (kk >> 2)];
            acc[r] = f4fma(hv.x, w0, acc[r]);
            acc[r] = f4fma(hv.y, w1, acc[r]);
            acc[r] = f4fma(hv.z, w2, acc[r]);
            acc[r] = f4fma(hv.w, w3, acc[r]);
        }
    }
    #pragma unroll
    for (int r = 0; r < 8; ++r) {
        int nd = row0 + r;
        if (nd < N) {
            ushort4 o;
            o.x = f2bf(acc[r].x); o.y = f2bf(acc[r].y);
            o.z = f2bf(acc[r].z); o.w = f2bf(acc[r].w);
            ((ushort4*)out)[(size_t)nd * D8 + cg] = o;
        }
    }
}

// ---------- CSR gather (bf16 T) + self-loop + bias + relu + LN stats ----------
// 16 nodes per 256-thr block; 16 lanes per node, uint4 = 8 bf16 ch per lane.
// One T-load instruction covers 4 rows (1 KB) -> 16 rows in flight per wave
// at MLP-4. (r8 lesson: LDS-atomic edge-parallel version was 3x WORSE.)
__launch_bounds__(256)
__global__ void k_gather(const unsigned short* __restrict__ T,
                         const int2* __restrict__ edata,
                         const int* __restrict__ rowptr, const float* __restrict__ dinv,
                         const float* __restrict__ bias, float* __restrict__ outA,
                         double* __restrict__ sums, int N) {
    int n = blockIdx.x * 16 + (threadIdx.x >> 4);
    int lane = threadIdx.x & 15;          // channels 8*lane .. 8*lane+7
    const uint4* T16 = (const uint4*)T;   // row stride = 16 uint4s (256 B)
    float ls = 0.f, lq = 0.f;
    if (n < N) {
        int e0 = rowptr[n], e1 = rowptr[n + 1];
        float acc[8];
        #pragma unroll
        for (int k = 0; k < 8; ++k) acc[k] = 0.f;
        int e = e0;
        for (; e + 4 <= e1; e += 4) {
            int2 d0 = edata[e + 0];
            int2 d1 = edata[e + 1];
            int2 d2 = edata[e + 2];
            int2 d3 = edata[e + 3];
            uint4 t0 = T16[(size_t)d0.x * 16 + lane];
            uint4 t1 = T16[(size_t)d1.x * 16 + lane];
            uint4 t2 = T16[(size_t)d2.x * 16 + lane];
            uint4 t3 = T16[(size_t)d3.x * 16 + lane];
            accum8(acc, __int_as_float(d0.y), t0);
            accum8(acc, __int_as_float(d1.y), t1);
            accum8(acc, __int_as_float(d2.y), t2);
            accum8(acc, __int_as_float(d3.y), t3);
        }
        for (; e < e1; ++e) {
            int2 d = edata[e];
            accum8(acc, __int_as_float(d.y), T16[(size_t)d.x * 16 + lane]);
        }
        // self-loop
        float di = dinv[n];
        accum8(acc, di * di, T16[(size_t)n * 16 + lane]);
        // bias + relu + write + LN stats
        const float4* b4 = (const float4*)bias;
        float4 blo = b4[2 * lane], bhi = b4[2 * lane + 1];
        float4 vlo, vhi;
        vlo.x = fmaxf(acc[0] + blo.x, 0.f);
        vlo.y = fmaxf(acc[1] + blo.y, 0.f);
        vlo.z = fmaxf(acc[2] + blo.z, 0.f);
        vlo.w = fmaxf(acc[3] + blo.w, 0.f);
        vhi.x = fmaxf(acc[4] + bhi.x, 0.f);
        vhi.y = fmaxf(acc[5] + bhi.y, 0.f);
        vhi.z = fmaxf(acc[6] + bhi.z, 0.f);
        vhi.w = fmaxf(acc[7] + bhi.w, 0.f);
        ((float4*)outA)[(size_t)n * D4 + 2 * lane + 0] = vlo;
        ((float4*)outA)[(size_t)n * D4 + 2 * lane + 1] = vhi;
        ls = (vlo.x + vlo.y + vlo.z + vlo.w) + (vhi.x + vhi.y + vhi.z + vhi.w);
        lq = vlo.x * vlo.x + vlo.y * vlo.y + vlo.z * vlo.z + vlo.w * vlo.w
           + vhi.x * vhi.x + vhi.y * vhi.y + vhi.z * vhi.z + vhi.w * vhi.w;
    }
    // wave64 reduce
    for (int off = 32; off; off >>= 1) {
        ls += __shfl_down(ls, off);
        lq += __shfl_down(lq, off);
    }
    __shared__ float ss[4], sq[4];
    int wid = threadIdx.x >> 6;
    if ((threadIdx.x & 63) == 0) { ss[wid] = ls; sq[wid] = lq; }
    __syncthreads();
    if (threadIdx.x == 0) {
        float S = ss[0] + ss[1] + ss[2] + ss[3];
        float Q = sq[0] + sq[1] + sq[2] + sq[3];
        atomicAdd(&sums[0], (double)S);
        atomicAdd(&sums[1], (double)Q);
    }
}

// ---------- global max pool per graph, applying final LN inline ----------
__launch_bounds__(512)
__global__ void k_pool(const float* __restrict__ A, const int* __restrict__ batch,
                       const float* __restrict__ lw, const float* __restrict__ lb,
                       const double* __restrict__ sums, float* __restrict__ g, int N) {
    int gi = blockIdx.x;
    int lo = 0, hi = N;
    while (lo < hi) { int mid = (lo + hi) >> 1; if (batch[mid] < gi) lo = mid + 1; else hi = mid; }
    int start = lo;
    hi = N;
    while (lo < hi) { int mid = (lo + hi) >> 1; if (batch[mid] < gi + 1) lo = mid + 1; else hi = mid; }
    int end = lo;

    int c = threadIdx.x & 127, sub = threadIdx.x >> 7;
    double M = (double)N * D;
    double m_ = sums[0] / M;
    double var = sums[1] / M - m_ * m_;
    float sd = sqrtf(var > 0.0 ? (float)var : 0.f);
    float inv = 1.f / (sd + 1e-5f);
    float s = inv * lw[c];
    float o = lb[c] - (float)m_ * s;

    float mx = -FLT_MAX;
    for (int node = start + sub; node < end; node += 4)
        mx = fmaxf(mx, fmaf(A[(size_t)node * D + c], s, o));

    __shared__ float red[4][128];
    red[sub][c] = mx;
    __syncthreads();
    if (sub == 0) {
        mx = fmaxf(fmaxf(red[0][c], red[1][c]), fmaxf(red[2][c], red[3][c]));
        g[gi * D + c] = mx;
    }
}

// ---------- t = tanh(g @ fc_w + fc_b) ----------
__global__ void k_fc(const float* __restrict__ g, const float* __restrict__ w,
                     const float* __restrict__ b, float* __restrict__ t) {
    __shared__ float row[D];
    int gi = blockIdx.x, c = threadIdx.x;
    row[c] = g[gi * D + c];
    __syncthreads();
    float acc = b[c];
    for (int k = 0; k < D; ++k) acc = fmaf(row[k], w[k * D + c], acc);
    t[gi * D + c] = tanhf(acc);
}

// ---------- out = t @ pred_w + pred_b ----------
__global__ void k_pred(const float* __restrict__ t, const float* __restrict__ w,
                       const float* __restrict__ b, float* __restrict__ out, int total) {
    int i = blockIdx.x * blockDim.x + threadIdx.x;
    if (i >= total) return;
    int gi = i / 10, j = i % 10;
    float acc = b[j];
    for (int k = 0; k < D; ++k) acc = fmaf(t[gi * D + k], w[k * 10 + j], acc);
    out[i] = acc;
}

extern "C" void kernel_launch(void* const* d_in, const int* in_sizes, int n_in,
                              void* d_out, int out_size, void* d_ws, size_t ws_size,
                              hipStream_t stream) {
    const float* x      = (const float*)d_in[0];
    const int*   src    = (const int*)d_in[1];
    const int*   dst    = (const int*)d_in[2];
    const int*   batch  = (const int*)d_in[3];
    const float* enc_w  = (const float*)d_in[4];
    const float* enc_b  = (const float*)d_in[5];
    const float* fc_w   = (const float*)d_in[6];
    const float* fc_b   = (const float*)d_in[7];
    const float* pred_w = (const float*)d_in[8];
    const float* pred_b = (const float*)d_in[9];

    int N = in_sizes[0] / 3;
    int E = in_sizes[1];
    int G = out_size / 10;

    char* ws = (char*)d_ws;
    size_t off = 0;
    auto align512 = [](size_t v) { return (v + 511) / 512 * 512; };
    float* dinv   = (float*)(ws + off); off += align512((size_t)N * 4);
    int*   cnt    = (int*)(ws + off);   off += align512((size_t)N * 4);
    int*   rowptr = (int*)(ws + off);   off += align512(((size_t)N + 1) * 4);
    int*   cur    = (int*)(ws + off);   off += align512((size_t)N * 4);
    int2*  edata  = (int2*)(ws + off);  off += align512((size_t)E * 8);
    float* A      = (float*)(ws + off); off += (size_t)N * D * 4;
    unsigned short* T = (unsigned short*)(ws + off); off += align512((size_t)N * D * 2);
    double* sums  = (double*)(ws + off); off += 512;
    float* wp     = (float*)(ws + off); off += (size_t)D * D * 4;
    float* konst  = (float*)(ws + off); off += align512((size_t)D * 4);
    float* gmax   = (float*)(ws + off); off += (size_t)G * D * 4;
    float* tb     = (float*)(ws + off); off += (size_t)G * D * 4;

    // ---- CSR build (per launch; inputs restored every call) ----
    hipMemsetAsync(cnt, 0, (size_t)N * 4, stream);
    k_count<<<(E + 255) / 256, 256, 0, stream>>>(dst, cnt, E);
    k_dinv<<<(N + 255) / 256, 256, 0, stream>>>(cnt, dinv, N);
    k_scan<<<1, 1024, 0, stream>>>(cnt, rowptr, cur, N);
    k_fill<<<(E + 255) / 256, 256, 0, stream>>>(src, dst, dinv, cur, edata, E);

    // ---- encoder ----
    int tot4 = N * D4;
    k_enc<<<(tot4 + 255) / 256, 256, 0, stream>>>(x, enc_w, enc_b, A, N);

    // ---- 4 GCN layers (LN of layer L-1 folded into layer L's weights) ----
    for (int L = 0; L < 4; ++L) {
        const float* w  = (const float*)d_in[10 + 4 * L];
        const float* b  = (const float*)d_in[11 + 4 * L];
        const float* lwp = L ? (const float*)d_in[12 + 4 * (L - 1)] : nullptr;
        const float* lbp = L ? (const float*)d_in[13 + 4 * (L - 1)] : nullptr;
        k_prep<<<9, 256, 0, stream>>>(w, lwp, lbp, sums, wp, konst, N);
        k_mm<<<(N + 63) / 64, 256, 0, stream>>>(A, wp, konst, T, N);
        hipMemsetAsync(sums, 0, 16, stream);
        k_gather<<<(N + 15) / 16, 256, 0, stream>>>(T, edata, rowptr, dinv, b, A, sums, N);
    }

    // ---- final LN applied inside pool ----
    const float* lw3 = (const float*)d_in[12 + 4 * 3];
    const float* lb3 = (const float*)d_in[13 + 4 * 3];
    k_pool<<<G, 512, 0, stream>>>(A, batch, lw3, lb3, sums, gmax, N);
    k_fc<<<G, D, 0, stream>>>(gmax, fc_w, fc_b, tb);
    k_pred<<<(G * 10 + 255) / 256, 256, 0, stream>>>(tb, pred_w, pred_b, (float*)d_out, G * 10);
}

// Round 10
// 785.319 us; speedup vs baseline: 3.1648x; 1.1501x over previous
//
#include <hip/hip_runtime.h>
#include <cfloat>
#include <cmath>

#define D 128
#define D4 32   // D/4 float4s per f32 row
#define D8 32   // D/4 ushort4s per bf16 row

// ---------- helpers ----------
__device__ __forceinline__ float4 f4fma(float s, float4 a, float4 acc) {
    acc.x = fmaf(s, a.x, acc.x);
    acc.y = fmaf(s, a.y, acc.y);
    acc.z = fmaf(s, a.z, acc.z);
    acc.w = fmaf(s, a.w, acc.w);
    return acc;
}

__device__ __forceinline__ unsigned short f2bf(float x) {
    unsigned int b = __float_as_uint(x);
    unsigned int r = (b + 0x7FFFu + ((b >> 16) & 1u)) >> 16;   // RNE
    return (unsigned short)r;
}

__device__ __forceinline__ float bf2f(unsigned short u) {
    return __uint_as_float(((unsigned int)u) << 16);
}

// accumulate 8 bf16 channels (one uint4) scaled by nrm into acc[8]
__device__ __forceinline__ void accum8(float* a, float nrm, uint4 t) {
    a[0] = fmaf(nrm, bf2f((unsigned short)(t.x & 0xFFFFu)), a[0]);
    a[1] = fmaf(nrm, bf2f((unsigned short)(t.x >> 16)), a[1]);
    a[2] = fmaf(nrm, bf2f((unsigned short)(t.y & 0xFFFFu)), a[2]);
    a[3] = fmaf(nrm, bf2f((unsigned short)(t.y >> 16)), a[3]);
    a[4] = fmaf(nrm, bf2f((unsigned short)(t.z & 0xFFFFu)), a[4]);
    a[5] = fmaf(nrm, bf2f((unsigned short)(t.z >> 16)), a[5]);
    a[6] = fmaf(nrm, bf2f((unsigned short)(t.w & 0xFFFFu)), a[6]);
    a[7] = fmaf(nrm, bf2f((unsigned short)(t.w >> 16)), a[7]);
}

// ---------- degree count (int) ----------
__global__ void k_count(const int* __restrict__ dst, int* __restrict__ cnt, int E) {
    int i = blockIdx.x * blockDim.x + threadIdx.x;
    if (i < E) atomicAdd(&cnt[dst[i]], 1);
}

// ---------- parallel scan, stage 1: per-256-chunk block sums ----------
__global__ void k_scan1(const int* __restrict__ cnt, int* __restrict__ bsum, int N) {
    __shared__ int red[256];
    int i = blockIdx.x * 256 + threadIdx.x;
    red[threadIdx.x] = (i < N) ? cnt[i] : 0;
    __syncthreads();
    for (int off = 128; off; off >>= 1) {
        if (threadIdx.x < off) red[threadIdx.x] += red[threadIdx.x + off];
        __syncthreads();
    }
    if (threadIdx.x == 0) bsum[blockIdx.x] = red[0];
}

// ---------- stage 2: single-block exclusive scan of block sums (NB<=256) ----
__global__ void k_scan2(int* __restrict__ bsum, int NB, int* __restrict__ rowptrN) {
    __shared__ int s[256];
    int t = threadIdx.x;
    int v = (t < NB) ? bsum[t] : 0;
    s[t] = v;
    __syncthreads();
    for (int off = 1; off < 256; off <<= 1) {
        int u = (t >= off) ? s[t - off] : 0;
        __syncthreads();
        s[t] += u;
        __syncthreads();
    }
    if (t < NB) bsum[t] = (t == 0) ? 0 : s[t - 1];
    if (t == 255) *rowptrN = s[255];     // rowptr[N] = E
}

// ---------- stage 3: per-chunk exclusive scan + offsets; also dinv ----------
__global__ void k_scan3(const int* __restrict__ cnt, const int* __restrict__ bsum,
                        int* __restrict__ rowptr, int* __restrict__ cur,
                        float* __restrict__ dinv, int N) {
    __shared__ int s[256];
    int i = blockIdx.x * 256 + threadIdx.x;
    int v = (i < N) ? cnt[i] : 0;
    s[threadIdx.x] = v;
    __syncthreads();
    for (int off = 1; off < 256; off <<= 1) {
        int u = (threadIdx.x >= off) ? s[threadIdx.x - off] : 0;
        __syncthreads();
        s[threadIdx.x] += u;
        __syncthreads();
    }
    if (i < N) {
        int excl = ((threadIdx.x == 0) ? 0 : s[threadIdx.x - 1]) + bsum[blockIdx.x];
        rowptr[i] = excl;
        cur[i] = excl;
        dinv[i] = 1.0f / sqrtf((float)v + 1.0f);   // +1 = self-loop
    }
}

// ---------- fill CSR edge data: (src, norm) sorted by dst ----------
__global__ void k_fill(const int* __restrict__ src, const int* __restrict__ dst,
                       const float* __restrict__ dinv, int* __restrict__ cur,
                       int2* __restrict__ edata, int E) {
    int e = blockIdx.x * blockDim.x + threadIdx.x;
    if (e >= E) return;
    int s = src[e], d = dst[e];
    int p = atomicAdd(&cur[d], 1);
    edata[p] = make_int2(s, __float_as_int(dinv[s] * dinv[d]));
}

// ---------- encoder: h = elu(x @ enc_w + enc_b), x:[N,3] ----------
__global__ void k_enc(const float* __restrict__ x, const float* __restrict__ w,
                      const float* __restrict__ b, float* __restrict__ h, int N) {
    int idx = blockIdx.x * blockDim.x + threadIdx.x;   // over N*D4
    if (idx >= N * D4) return;
    int n = idx >> 5, c4 = idx & 31;
    const float4* w4 = (const float4*)w;
    float4 b4 = ((const float4*)b)[c4];
    float x0 = x[n * 3 + 0], x1 = x[n * 3 + 1], x2 = x[n * 3 + 2];
    float4 v = b4;
    v = f4fma(x0, w4[0 * D4 + c4], v);
    v = f4fma(x1, w4[1 * D4 + c4], v);
    v = f4fma(x2, w4[2 * D4 + c4], v);
    v.x = v.x > 0.f ? v.x : expm1f(v.x);
    v.y = v.y > 0.f ? v.y : expm1f(v.y);
    v.z = v.z > 0.f ? v.z : expm1f(v.z);
    v.w = v.w > 0.f ? v.w : expm1f(v.w);
    ((float4*)h)[idx] = v;
}

// ---------- per-layer LN-fold: W' = s_c * W, konst_j = sum_c o_c * W_cj ----------
__global__ void k_prep(const float* __restrict__ w, const float* __restrict__ lw,
                       const float* __restrict__ lb, const double* __restrict__ sums,
                       float* __restrict__ wout, float* __restrict__ konst, int N) {
    __shared__ float sc[D], of[D];
    float mu = 0.f, inv = 1.f;
    if (lw) {
        double M = (double)N * D;
        double m = sums[0] / M;
        double var = sums[1] / M - m * m;
        float sd = sqrtf(var > 0.0 ? (float)var : 0.f);
        inv = 1.f / (sd + 1e-5f);
        mu = (float)m;
    }
    for (int i = threadIdx.x; i < D; i += blockDim.x) {
        float l = lw ? lw[i] : 1.f;
        float s = inv * l;
        sc[i] = s;
        of[i] = (lw ? lb[i] : 0.f) - mu * s;
    }
    __syncthreads();
    if (blockIdx.x < 8) {
        int chunk = D * D / 8;   // 2048
        int base = blockIdx.x * chunk;
        for (int i = threadIdx.x; i < chunk; i += blockDim.x) {
            int idx = base + i;
            wout[idx] = sc[idx >> 7] * w[idx];
        }
    } else {
        for (int j = threadIdx.x; j < D; j += blockDim.x) {
            float acc = 0.f;
            for (int c = 0; c < D; ++c) acc = fmaf(of[c], w[c * D + j], acc);
            konst[j] = acc;
        }
    }
}

// ---------- dense matmul: T[N,128](bf16) = h[N,128] @ wp[128,128] + konst ----
__launch_bounds__(256)
__global__ void k_mm(const float* __restrict__ h, const float* __restrict__ wp,
                     const float* __restrict__ konst, unsigned short* __restrict__ out,
                     int N) {
    __shared__ float wl[D * D];          // 64 KB
    float4* wl4 = (float4*)wl;
    const float4* wg4 = (const float4*)wp;
    for (int i = threadIdx.x; i < D * D4; i += 256) wl4[i] = wg4[i];
    __syncthreads();

    int cg = threadIdx.x & 31;
    int rg = threadIdx.x >> 5;
    int row0 = blockIdx.x * 64 + rg * 8;
    const float4* h4 = (const float4*)h;
    float4 k4 = ((const float4*)konst)[cg];

    float4 acc[8];
    #pragma unroll
    for (int r = 0; r < 8; ++r) acc[r] = k4;

    int nodes[8];
    #pragma unroll
    for (int r = 0; r < 8; ++r) { int nd = row0 + r; nodes[r] = nd < N ? nd : N - 1; }

    for (int kk = 0; kk < D; kk += 4) {
        float4 w0 = wl4[(kk + 0) * D4 + cg];
        float4 w1 = wl4[(kk + 1) * D4 + cg];
        float4 w2 = wl4[(kk + 2) * D4 + cg];
        float4 w3 = wl4[(kk + 3) * D4 + cg];
        #pragma unroll
        for (int r = 0; r < 8; ++r) {
            float4 hv = h4[(size_t)nodes[r] * D4 + (kk >> 2)];
            acc[r] = f4fma(hv.x, w0, acc[r]);
            acc[r] = f4fma(hv.y, w1, acc[r]);
            acc[r] = f4fma(hv.z, w2, acc[r]);
            acc[r] = f4fma(hv.w, w3, acc[r]);
        }
    }
    #pragma unroll
    for (int r = 0; r < 8; ++r) {
        int nd = row0 + r;
        if (nd < N) {
            ushort4 o;
            o.x = f2bf(acc[r].x); o.y = f2bf(acc[r].y);
            o.z = f2bf(acc[r].z); o.w = f2bf(acc[r].w);
            ((ushort4*)out)[(size_t)nd * D8 + cg] = o;
        }
    }
}

// ---------- CSR gather (bf16 T) + self-loop + bias + relu + LN stats ----------
// 16 nodes per 256-thr block; 16 lanes per node, uint4 = 8 bf16 ch per lane.
__launch_bounds__(256)
__global__ void k_gather(const unsigned short* __restrict__ T,
                         const int2* __restrict__ edata,
                         const int* __restrict__ rowptr, const float* __restrict__ dinv,
                         const float* __restrict__ bias, float* __restrict__ outA,
                         double* __restrict__ sums, int N) {
    int n = blockIdx.x * 16 + (threadIdx.x >> 4);
    int lane = threadIdx.x & 15;          // channels 8*lane .. 8*lane+7
    const uint4* T16 = (const uint4*)T;   // row stride = 16 uint4s (256 B)
    float ls = 0.f, lq = 0.f;
    if (n < N) {
        int e0 = rowptr[n], e1 = rowptr[n + 1];
        float acc[8];
        #pragma unroll
        for (int k = 0; k < 8; ++k) acc[k] = 0.f;
        int e = e0;
        for (; e + 4 <= e1; e += 4) {
            int2 d0 = edata[e + 0];
            int2 d1 = edata[e + 1];
            int2 d2 = edata[e + 2];
            int2 d3 = edata[e + 3];
            uint4 t0 = T16[(size_t)d0.x * 16 + lane];
            uint4 t1 = T16[(size_t)d1.x * 16 + lane];
            uint4 t2 = T16[(size_t)d2.x * 16 + lane];
            uint4 t3 = T16[(size_t)d3.x * 16 + lane];
            accum8(acc, __int_as_float(d0.y), t0);
            accum8(acc, __int_as_float(d1.y), t1);
            accum8(acc, __int_as_float(d2.y), t2);
            accum8(acc, __int_as_float(d3.y), t3);
        }
        for (; e < e1; ++e) {
            int2 d = edata[e];
            accum8(acc, __int_as_float(d.y), T16[(size_t)d.x * 16 + lane]);
        }
        // self-loop
        float di = dinv[n];
        accum8(acc, di * di, T16[(size_t)n * 16 + lane]);
        // bias + relu + write + LN stats
        const float4* b4 = (const float4*)bias;
        float4 blo = b4[2 * lane], bhi = b4[2 * lane + 1];
        float4 vlo, vhi;
        vlo.x = fmaxf(acc[0] + blo.x, 0.f);
        vlo.y = fmaxf(acc[1] + blo.y, 0.f);
        vlo.z = fmaxf(acc[2] + blo.z, 0.f);
        vlo.w = fmaxf(acc[3] + blo.w, 0.f);
        vhi.x = fmaxf(acc[4] + bhi.x, 0.f);
        vhi.y = fmaxf(acc[5] + bhi.y, 0.f);
        vhi.z = fmaxf(acc[6] + bhi.z, 0.f);
        vhi.w = fmaxf(acc[7] + bhi.w, 0.f);
        ((float4*)outA)[(size_t)n * D4 + 2 * lane + 0] = vlo;
        ((float4*)outA)[(size_t)n * D4 + 2 * lane + 1] = vhi;
        ls = (vlo.x + vlo.y + vlo.z + vlo.w) + (vhi.x + vhi.y + vhi.z + vhi.w);
        lq = vlo.x * vlo.x + vlo.y * vlo.y + vlo.z * vlo.z + vlo.w * vlo.w
           + vhi.x * vhi.x + vhi.y * vhi.y + vhi.z * vhi.z + vhi.w * vhi.w;
    }
    // wave64 reduce
    for (int off = 32; off; off >>= 1) {
        ls += __shfl_down(ls, off);
        lq += __shfl_down(lq, off);
    }
    __shared__ float ss[4], sq[4];
    int wid = threadIdx.x >> 6;
    if ((threadIdx.x & 63) == 0) { ss[wid] = ls; sq[wid] = lq; }
    __syncthreads();
    if (threadIdx.x == 0) {
        float S = ss[0] + ss[1] + ss[2] + ss[3];
        float Q = sq[0] + sq[1] + sq[2] + sq[3];
        atomicAdd(&sums[0], (double)S);
        atomicAdd(&sums[1], (double)Q);
    }
}

// ---------- fused tail: pool (with final LN) + tanh-FC + pred ----------
// one 512-thr block per graph
__launch_bounds__(512)
__global__ void k_tail(const float* __restrict__ A, const int* __restrict__ batch,
                       const float* __restrict__ lw, const float* __restrict__ lb,
                       const double* __restrict__ sums,
                       const float* __restrict__ fc_w, const float* __restrict__ fc_b,
                       const float* __restrict__ pred_w, const float* __restrict__ pred_b,
                       float* __restrict__ out, int N) {
    int gi = blockIdx.x;
    int lo = 0, hi = N;
    while (lo < hi) { int mid = (lo + hi) >> 1; if (batch[mid] < gi) lo = mid + 1; else hi = mid; }
    int start = lo;
    hi = N;
    while (lo < hi) { int mid = (lo + hi) >> 1; if (batch[mid] < gi + 1) lo = mid + 1; else hi = mid; }
    int end = lo;

    int c = threadIdx.x & 127, sub = threadIdx.x >> 7;
    double M = (double)N * D;
    double m_ = sums[0] / M;
    double var = sums[1] / M - m_ * m_;
    float sd = sqrtf(var > 0.0 ? (float)var : 0.f);
    float inv = 1.f / (sd + 1e-5f);
    float s = inv * lw[c];
    float o = lb[c] - (float)m_ * s;

    float mx = -FLT_MAX;
    for (int node = start + sub; node < end; node += 4)
        mx = fmaxf(mx, fmaf(A[(size_t)node * D + c], s, o));

    __shared__ float red[4][128];
    __shared__ float gm[128], tr[128];
    red[sub][c] = mx;
    __syncthreads();
    if (sub == 0)
        gm[c] = fmaxf(fmaxf(red[0][c], red[1][c]), fmaxf(red[2][c], red[3][c]));
    __syncthreads();
    // fc: t = tanh(gm @ fc_w + fc_b)
    if (threadIdx.x < 128) {
        float acc = fc_b[c];
        for (int k = 0; k < D; ++k) acc = fmaf(gm[k], fc_w[k * D + c], acc);
        tr[c] = tanhf(acc);
    }
    __syncthreads();
    // pred: out = t @ pred_w + pred_b
    if (threadIdx.x < 10) {
        int j = threadIdx.x;
        float acc = pred_b[j];
        for (int k = 0; k < D; ++k) acc = fmaf(tr[k], pred_w[k * 10 + j], acc);
        out[gi * 10 + j] = acc;
    }
}

extern "C" void kernel_launch(void* const* d_in, const int* in_sizes, int n_in,
                              void* d_out, int out_size, void* d_ws, size_t ws_size,
                              hipStream_t stream) {
    const float* x      = (const float*)d_in[0];
    const int*   src    = (const int*)d_in[1];
    const int*   dst    = (const int*)d_in[2];
    const int*   batch  = (const int*)d_in[3];
    const float* enc_w  = (const float*)d_in[4];
    const float* enc_b  = (const float*)d_in[5];
    const float* fc_w   = (const float*)d_in[6];
    const float* fc_b   = (const float*)d_in[7];
    const float* pred_w = (const float*)d_in[8];
    const float* pred_b = (const float*)d_in[9];

    int N = in_sizes[0] / 3;
    int E = in_sizes[1];
    int G = out_size / 10;
    int NB = (N + 255) / 256;            // scan chunks (<=256 for N<=65536)

    char* ws = (char*)d_ws;
    size_t off = 0;
    auto align512 = [](size_t v) { return (v + 511) / 512 * 512; };
    int*   cnt    = (int*)(ws + off);   off += align512((size_t)N * 4);
    double* sums  = (double*)(ws + off); off += 512;   // 4 layer slots (2 dbl each)
    float* dinv   = (float*)(ws + off); off += align512((size_t)N * 4);
    int*   rowptr = (int*)(ws + off);   off += align512(((size_t)N + 1) * 4);
    int*   cur    = (int*)(ws + off);   off += align512((size_t)N * 4);
    int*   bsum   = (int*)(ws + off);   off += align512(1024);
    int2*  edata  = (int2*)(ws + off);  off += align512((size_t)E * 8);
    float* A      = (float*)(ws + off); off += (size_t)N * D * 4;
    unsigned short* T = (unsigned short*)(ws + off); off += align512((size_t)N * D * 2);
    float* wp     = (float*)(ws + off); off += (size_t)D * D * 4;
    float* konst  = (float*)(ws + off); off += align512((size_t)D * 4);

    // ---- CSR build; one memset covers cnt + sums (adjacent in ws) ----
    hipMemsetAsync(cnt, 0, align512((size_t)N * 4) + 512, stream);
    k_count<<<(E + 255) / 256, 256, 0, stream>>>(dst, cnt, E);
    k_scan1<<<NB, 256, 0, stream>>>(cnt, bsum, N);
    k_scan2<<<1, 256, 0, stream>>>(bsum, NB, rowptr + N);
    k_scan3<<<NB, 256, 0, stream>>>(cnt, bsum, rowptr, cur, dinv, N);
    k_fill<<<(E + 255) / 256, 256, 0, stream>>>(src, dst, dinv, cur, edata, E);

    // ---- encoder ----
    int tot4 = N * D4;
    k_enc<<<(tot4 + 255) / 256, 256, 0, stream>>>(x, enc_w, enc_b, A, N);

    // ---- 4 GCN layers (LN of layer L-1 folded into layer L's weights) ----
    for (int L = 0; L < 4; ++L) {
        const float* w  = (const float*)d_in[10 + 4 * L];
        const float* b  = (const float*)d_in[11 + 4 * L];
        const float* lwp = L ? (const float*)d_in[12 + 4 * (L - 1)] : nullptr;
        const float* lbp = L ? (const float*)d_in[13 + 4 * (L - 1)] : nullptr;
        k_prep<<<9, 256, 0, stream>>>(w, lwp, lbp, &sums[2 * (L ? L - 1 : 0)], wp, konst, N);
        k_mm<<<(N + 63) / 64, 256, 0, stream>>>(A, wp, konst, T, N);
        k_gather<<<(N + 15) / 16, 256, 0, stream>>>(T, edata, rowptr, dinv, b, A, &sums[2 * L], N);
    }

    // ---- fused pool + fc + pred (final LN inline) ----
    const float* lw3 = (const float*)d_in[12 + 4 * 3];
    const float* lb3 = (const float*)d_in[13 + 4 * 3];
    k_tail<<<G, 512, 0, stream>>>(A, batch, lw3, lb3, &sums[6],
                                  fc_w, fc_b, pred_w, pred_b, (float*)d_out, N);
}

// Round 11
// 663.761 us; speedup vs baseline: 3.7444x; 1.1831x over previous
//
#include <hip/hip_runtime.h>
#include <cfloat>
#include <cmath>

#define D 128
#define D4 32   // D/4 float4s per f32 row
#define D8 32   // D/4 ushort4s per bf16 row

typedef __attribute__((ext_vector_type(8))) short short8;
typedef __attribute__((ext_vector_type(4))) float f32x4;

// ---------- helpers ----------
__device__ __forceinline__ float4 f4fma(float s, float4 a, float4 acc) {
    acc.x = fmaf(s, a.x, acc.x);
    acc.y = fmaf(s, a.y, acc.y);
    acc.z = fmaf(s, a.z, acc.z);
    acc.w = fmaf(s, a.w, acc.w);
    return acc;
}

__device__ __forceinline__ unsigned short f2bf(float x) {
    unsigned int b = __float_as_uint(x);
    unsigned int r = (b + 0x7FFFu + ((b >> 16) & 1u)) >> 16;   // RNE
    return (unsigned short)r;
}

__device__ __forceinline__ unsigned int pack2bf(float a, float b) {
    return (unsigned int)f2bf(a) | ((unsigned int)f2bf(b) << 16);
}

__device__ __forceinline__ float bf2f(unsigned short u) {
    return __uint_as_float(((unsigned int)u) << 16);
}

// accumulate 8 bf16 channels (one uint4) scaled by nrm into acc[8]
__device__ __forceinline__ void accum8(float* a, float nrm, uint4 t) {
    a[0] = fmaf(nrm, bf2f((unsigned short)(t.x & 0xFFFFu)), a[0]);
    a[1] = fmaf(nrm, bf2f((unsigned short)(t.x >> 16)), a[1]);
    a[2] = fmaf(nrm, bf2f((unsigned short)(t.y & 0xFFFFu)), a[2]);
    a[3] = fmaf(nrm, bf2f((unsigned short)(t.y >> 16)), a[3]);
    a[4] = fmaf(nrm, bf2f((unsigned short)(t.z & 0xFFFFu)), a[4]);
    a[5] = fmaf(nrm, bf2f((unsigned short)(t.z >> 16)), a[5]);
    a[6] = fmaf(nrm, bf2f((unsigned short)(t.w & 0xFFFFu)), a[6]);
    a[7] = fmaf(nrm, bf2f((unsigned short)(t.w >> 16)), a[7]);
}

// ---------- degree count (int) ----------
__global__ void k_count(const int* __restrict__ dst, int* __restrict__ cnt, int E) {
    int i = blockIdx.x * blockDim.x + threadIdx.x;
    if (i < E) atomicAdd(&cnt[dst[i]], 1);
}

// ---------- parallel scan, stage 1: per-256-chunk block sums ----------
__global__ void k_scan1(const int* __restrict__ cnt, int* __restrict__ bsum, int N) {
    __shared__ int red[256];
    int i = blockIdx.x * 256 + threadIdx.x;
    red[threadIdx.x] = (i < N) ? cnt[i] : 0;
    __syncthreads();
    for (int off = 128; off; off >>= 1) {
        if (threadIdx.x < off) red[threadIdx.x] += red[threadIdx.x + off];
        __syncthreads();
    }
    if (threadIdx.x == 0) bsum[blockIdx.x] = red[0];
}

// ---------- stage 2: single-block exclusive scan of block sums (NB<=256) ----
__global__ void k_scan2(int* __restrict__ bsum, int NB, int* __restrict__ rowptrN) {
    __shared__ int s[256];
    int t = threadIdx.x;
    int v = (t < NB) ? bsum[t] : 0;
    s[t] = v;
    __syncthreads();
    for (int off = 1; off < 256; off <<= 1) {
        int u = (t >= off) ? s[t - off] : 0;
        __syncthreads();
        s[t] += u;
        __syncthreads();
    }
    if (t < NB) bsum[t] = (t == 0) ? 0 : s[t - 1];
    if (t == 255) *rowptrN = s[255];     // rowptr[N] = E
}

// ---------- stage 3: per-chunk exclusive scan + offsets; also dinv ----------
__global__ void k_scan3(const int* __restrict__ cnt, const int* __restrict__ bsum,
                        int* __restrict__ rowptr, int* __restrict__ cur,
                        float* __restrict__ dinv, int N) {
    __shared__ int s[256];
    int i = blockIdx.x * 256 + threadIdx.x;
    int v = (i < N) ? cnt[i] : 0;
    s[threadIdx.x] = v;
    __syncthreads();
    for (int off = 1; off < 256; off <<= 1) {
        int u = (threadIdx.x >= off) ? s[threadIdx.x - off] : 0;
        __syncthreads();
        s[threadIdx.x] += u;
        __syncthreads();
    }
    if (i < N) {
        int excl = ((threadIdx.x == 0) ? 0 : s[threadIdx.x - 1]) + bsum[blockIdx.x];
        rowptr[i] = excl;
        cur[i] = excl;
        dinv[i] = 1.0f / sqrtf((float)v + 1.0f);   // +1 = self-loop
    }
}

// ---------- fill CSR edge data: (src, norm) sorted by dst ----------
__global__ void k_fill(const int* __restrict__ src, const int* __restrict__ dst,
                       const float* __restrict__ dinv, int* __restrict__ cur,
                       int2* __restrict__ edata, int E) {
    int e = blockIdx.x * blockDim.x + threadIdx.x;
    if (e >= E) return;
    int s = src[e], d = dst[e];
    int p = atomicAdd(&cur[d], 1);
    edata[p] = make_int2(s, __float_as_int(dinv[s] * dinv[d]));
}

// ---------- encoder: h = elu(x @ enc_w + enc_b), x:[N,3] ----------
__global__ void k_enc(const float* __restrict__ x, const float* __restrict__ w,
                      const float* __restrict__ b, float* __restrict__ h, int N) {
    int idx = blockIdx.x * blockDim.x + threadIdx.x;   // over N*D4
    if (idx >= N * D4) return;
    int n = idx >> 5, c4 = idx & 31;
    const float4* w4 = (const float4*)w;
    float4 b4 = ((const float4*)b)[c4];
    float x0 = x[n * 3 + 0], x1 = x[n * 3 + 1], x2 = x[n * 3 + 2];
    float4 v = b4;
    v = f4fma(x0, w4[0 * D4 + c4], v);
    v = f4fma(x1, w4[1 * D4 + c4], v);
    v = f4fma(x2, w4[2 * D4 + c4], v);
    v.x = v.x > 0.f ? v.x : expm1f(v.x);
    v.y = v.y > 0.f ? v.y : expm1f(v.y);
    v.z = v.z > 0.f ? v.z : expm1f(v.z);
    v.w = v.w > 0.f ? v.w : expm1f(v.w);
    ((float4*)h)[idx] = v;
}

// ---------- per-layer LN-fold, bf16 transposed weights ----------
// wt[n][k] = bf16( sc_k * W[k][n] );  konst_j = sum_c of_c * W[c][j]  (f32)
__global__ void k_prep(const float* __restrict__ w, const float* __restrict__ lw,
                       const float* __restrict__ lb, const double* __restrict__ sums,
                       unsigned short* __restrict__ wt, float* __restrict__ konst, int N) {
    __shared__ float sc[D], of[D];
    float mu = 0.f, inv = 1.f;
    if (lw) {
        double M = (double)N * D;
        double m = sums[0] / M;
        double var = sums[1] / M - m * m;
        float sd = sqrtf(var > 0.0 ? (float)var : 0.f);
        inv = 1.f / (sd + 1e-5f);
        mu = (float)m;
    }
    for (int i = threadIdx.x; i < D; i += blockDim.x) {
        float l = lw ? lw[i] : 1.f;
        float s = inv * l;
        sc[i] = s;
        of[i] = (lw ? lb[i] : 0.f) - mu * s;
    }
    __syncthreads();
    if (blockIdx.x < 8) {
        int nl = threadIdx.x & 15;       // output col group
        int ck = threadIdx.x >> 4;       // k-chunk 0..15 (8 k each)
        int n = blockIdx.x * 16 + nl;
        unsigned int p[4];
        #pragma unroll
        for (int q = 0; q < 4; ++q) {
            int k0 = ck * 8 + 2 * q;
            float v0 = sc[k0 + 0] * w[(k0 + 0) * D + n];
            float v1 = sc[k0 + 1] * w[(k0 + 1) * D + n];
            p[q] = pack2bf(v0, v1);
        }
        uint4 u = make_uint4(p[0], p[1], p[2], p[3]);
        ((uint4*)(wt + (size_t)n * D))[ck] = u;
    } else {
        for (int j = threadIdx.x; j < D; j += blockDim.x) {
            float acc = 0.f;
            for (int c = 0; c < D; ++c) acc = fmaf(of[c], w[c * D + j], acc);
            konst[j] = acc;
        }
    }
}

// ---------- MFMA matmul: T[N,128](bf16) = A[N,128](f32) @ W + konst ----------
// 256 thr = 4 waves; block tile 64 rows x 128 cols; K=128 in 4 steps of 32.
// LDS: A-tile bf16 [64][128] + Wt bf16 [128][128], XOR-swizzled (G4).
__launch_bounds__(256)
__global__ void k_mm(const float* __restrict__ h, const unsigned short* __restrict__ wt,
                     const float* __restrict__ konst, unsigned short* __restrict__ out,
                     int N) {
    __shared__ uint4 a_lds4[1024];       // 16 KB
    __shared__ uint4 w_lds4[2048];       // 32 KB
    char* a_lds = (char*)a_lds4;
    char* w_lds = (char*)w_lds4;
    int row0 = blockIdx.x * 64;

    // stage Wt (linear global, swizzled LDS): uint4 i -> row n=i>>4
    const uint4* wg = (const uint4*)wt;
    for (int i = threadIdx.x; i < 2048; i += 256) {
        int n = i >> 4;
        int byte = (i << 4) ^ ((n & 7) << 4);
        *(uint4*)(w_lds + byte) = wg[i];
    }
    // stage A tile: f32 -> bf16, swizzled
    for (int i = threadIdx.x; i < 1024; i += 256) {
        int r = i >> 4;
        int node = row0 + r; node = node < N ? node : N - 1;
        const float4* hp = (const float4*)(h + (size_t)node * D) + (i & 15) * 2;
        float4 lo = hp[0], hi = hp[1];
        uint4 p = make_uint4(pack2bf(lo.x, lo.y), pack2bf(lo.z, lo.w),
                             pack2bf(hi.x, hi.y), pack2bf(hi.z, hi.w));
        int byte = (i << 4) ^ ((r & 7) << 4);
        *(uint4*)(a_lds + byte) = p;
    }
    __syncthreads();

    int wv = threadIdx.x >> 6;           // wave id: rows wv*16..wv*16+15
    int lane = threadIdx.x & 63;
    int lrow = lane & 15;                // A-row / C-col within tile
    int kg = lane >> 4;                  // k-group 0..3

    f32x4 acc[8];
    #pragma unroll
    for (int ct = 0; ct < 8; ++ct) {
        float kc = konst[ct * 16 + lrow];
        acc[ct] = (f32x4){kc, kc, kc, kc};
    }

    #pragma unroll
    for (int ks = 0; ks < 4; ++ks) {
        int ar = wv * 16 + lrow;
        int abyte = (ar * 256 + ks * 64 + kg * 16) ^ ((ar & 7) << 4);
        short8 a = *(short8*)(a_lds + abyte);
        #pragma unroll
        for (int ct = 0; ct < 8; ++ct) {
            int wr = ct * 16 + lrow;
            int wbyte = (wr * 256 + ks * 64 + kg * 16) ^ ((wr & 7) << 4);
            short8 b = *(short8*)(w_lds + wbyte);
            acc[ct] = __builtin_amdgcn_mfma_f32_16x16x32_bf16(a, b, acc[ct], 0, 0, 0);
        }
    }

    // C/D: col = lane&15, row = kg*4 + reg  (m89-verified)
    #pragma unroll
    for (int ct = 0; ct < 8; ++ct) {
        #pragma unroll
        for (int r = 0; r < 4; ++r) {
            int row = row0 + wv * 16 + kg * 4 + r;
            if (row < N) out[(size_t)row * D + ct * 16 + lrow] = f2bf(acc[ct][r]);
        }
    }
}

// ---------- CSR gather (bf16 T) + self-loop + bias + relu + LN stats ----------
// 16 nodes per 256-thr block; 16 lanes per node, uint4 = 8 bf16 ch per lane.
// MLP-8 main loop (32 rows in flight per wave), then 4, then scalar.
__launch_bounds__(256)
__global__ void k_gather(const unsigned short* __restrict__ T,
                         const int2* __restrict__ edata,
                         const int* __restrict__ rowptr, const float* __restrict__ dinv,
                         const float* __restrict__ bias, float* __restrict__ outA,
                         double* __restrict__ sums, int N) {
    int n = blockIdx.x * 16 + (threadIdx.x >> 4);
    int lane = threadIdx.x & 15;          // channels 8*lane .. 8*lane+7
    const uint4* T16 = (const uint4*)T;   // row stride = 16 uint4s (256 B)
    float ls = 0.f, lq = 0.f;
    if (n < N) {
        int e0 = rowptr[n], e1 = rowptr[n + 1];
        float acc[8];
        #pragma unroll
        for (int k = 0; k < 8; ++k) acc[k] = 0.f;
        int e = e0;
        for (; e + 8 <= e1; e += 8) {
            int2 ed[8]; uint4 tv[8];
            #pragma unroll
            for (int j = 0; j < 8; ++j) ed[j] = edata[e + j];
            #pragma unroll
            for (int j = 0; j < 8; ++j) tv[j] = T16[(size_t)ed[j].x * 16 + lane];
            #pragma unroll
            for (int j = 0; j < 8; ++j) accum8(acc, __int_as_float(ed[j].y), tv[j]);
        }
        for (; e + 4 <= e1; e += 4) {
            int2 ed[4]; uint4 tv[4];
            #pragma unroll
            for (int j = 0; j < 4; ++j) ed[j] = edata[e + j];
            #pragma unroll
            for (int j = 0; j < 4; ++j) tv[j] = T16[(size_t)ed[j].x * 16 + lane];
            #pragma unroll
            for (int j = 0; j < 4; ++j) accum8(acc, __int_as_float(ed[j].y), tv[j]);
        }
        for (; e < e1; ++e) {
            int2 d = edata[e];
            accum8(acc, __int_as_float(d.y), T16[(size_t)d.x * 16 + lane]);
        }
        // self-loop
        float di = dinv[n];
        accum8(acc, di * di, T16[(size_t)n * 16 + lane]);
        // bias + relu + write + LN stats
        const float4* b4 = (const float4*)bias;
        float4 blo = b4[2 * lane], bhi = b4[2 * lane + 1];
        float4 vlo, vhi;
        vlo.x = fmaxf(acc[0] + blo.x, 0.f);
        vlo.y = fmaxf(acc[1] + blo.y, 0.f);
        vlo.z = fmaxf(acc[2] + blo.z, 0.f);
        vlo.w = fmaxf(acc[3] + blo.w, 0.f);
        vhi.x = fmaxf(acc[4] + bhi.x, 0.f);
        vhi.y = fmaxf(acc[5] + bhi.y, 0.f);
        vhi.z = fmaxf(acc[6] + bhi.z, 0.f);
        vhi.w = fmaxf(acc[7] + bhi.w, 0.f);
        ((float4*)outA)[(size_t)n * D4 + 2 * lane + 0] = vlo;
        ((float4*)outA)[(size_t)n * D4 + 2 * lane + 1] = vhi;
        ls = (vlo.x + vlo.y + vlo.z + vlo.w) + (vhi.x + vhi.y + vhi.z + vhi.w);
        lq = vlo.x * vlo.x + vlo.y * vlo.y + vlo.z * vlo.z + vlo.w * vlo.w
           + vhi.x * vhi.x + vhi.y * vhi.y + vhi.z * vhi.z + vhi.w * vhi.w;
    }
    // wave64 reduce
    for (int off = 32; off; off >>= 1) {
        ls += __shfl_down(ls, off);
        lq += __shfl_down(lq, off);
    }
    __shared__ float ss[4], sq[4];
    int wid = threadIdx.x >> 6;
    if ((threadIdx.x & 63) == 0) { ss[wid] = ls; sq[wid] = lq; }
    __syncthreads();
    if (threadIdx.x == 0) {
        float S = ss[0] + ss[1] + ss[2] + ss[3];
        float Q = sq[0] + sq[1] + sq[2] + sq[3];
        atomicAdd(&sums[0], (double)S);
        atomicAdd(&sums[1], (double)Q);
    }
}

// ---------- fused tail: pool (with final LN) + tanh-FC + pred ----------
__launch_bounds__(512)
__global__ void k_tail(const float* __restrict__ A, const int* __restrict__ batch,
                       const float* __restrict__ lw, const float* __restrict__ lb,
                       const double* __restrict__ sums,
                       const float* __restrict__ fc_w, const float* __restrict__ fc_b,
                       const float* __restrict__ pred_w, const float* __restrict__ pred_b,
                       float* __restrict__ out, int N) {
    int gi = blockIdx.x;
    int lo = 0, hi = N;
    while (lo < hi) { int mid = (lo + hi) >> 1; if (batch[mid] < gi) lo = mid + 1; else hi = mid; }
    int start = lo;
    hi = N;
    while (lo < hi) { int mid = (lo + hi) >> 1; if (batch[mid] < gi + 1) lo = mid + 1; else hi = mid; }
    int end = lo;

    int c = threadIdx.x & 127, sub = threadIdx.x >> 7;
    double M = (double)N * D;
    double m_ = sums[0] / M;
    double var = sums[1] / M - m_ * m_;
    float sd = sqrtf(var > 0.0 ? (float)var : 0.f);
    float inv = 1.f / (sd + 1e-5f);
    float s = inv * lw[c];
    float o = lb[c] - (float)m_ * s;

    float mx = -FLT_MAX;
    for (int node = start + sub; node < end; node += 4)
        mx = fmaxf(mx, fmaf(A[(size_t)node * D + c], s, o));

    __shared__ float red[4][128];
    __shared__ float gm[128], tr[128];
    red[sub][c] = mx;
    __syncthreads();
    if (sub == 0)
        gm[c] = fmaxf(fmaxf(red[0][c], red[1][c]), fmaxf(red[2][c], red[3][c]));
    __syncthreads();
    if (threadIdx.x < 128) {
        float acc = fc_b[c];
        for (int k = 0; k < D; ++k) acc = fmaf(gm[k], fc_w[k * D + c], acc);
        tr[c] = tanhf(acc);
    }
    __syncthreads();
    if (threadIdx.x < 10) {
        int j = threadIdx.x;
        float acc = pred_b[j];
        for (int k = 0; k < D; ++k) acc = fmaf(tr[k], pred_w[k * 10 + j], acc);
        out[gi * 10 + j] = acc;
    }
}

extern "C" void kernel_launch(void* const* d_in, const int* in_sizes, int n_in,
                              void* d_out, int out_size, void* d_ws, size_t ws_size,
                              hipStream_t stream) {
    const float* x      = (const float*)d_in[0];
    const int*   src    = (const int*)d_in[1];
    const int*   dst    = (const int*)d_in[2];
    const int*   batch  = (const int*)d_in[3];
    const float* enc_w  = (const float*)d_in[4];
    const float* enc_b  = (const float*)d_in[5];
    const float* fc_w   = (const float*)d_in[6];
    const float* fc_b   = (const float*)d_in[7];
    const float* pred_w = (const float*)d_in[8];
    const float* pred_b = (const float*)d_in[9];

    int N = in_sizes[0] / 3;
    int E = in_sizes[1];
    int G = out_size / 10;
    int NB = (N + 255) / 256;

    char* ws = (char*)d_ws;
    size_t off = 0;
    auto align512 = [](size_t v) { return (v + 511) / 512 * 512; };
    int*   cnt    = (int*)(ws + off);   off += align512((size_t)N * 4);
    double* sums  = (double*)(ws + off); off += 512;   // 4 layer slots (2 dbl each)
    float* dinv   = (float*)(ws + off); off += align512((size_t)N * 4);
    int*   rowptr = (int*)(ws + off);   off += align512(((size_t)N + 1) * 4);
    int*   cur    = (int*)(ws + off);   off += align512((size_t)N * 4);
    int*   bsum   = (int*)(ws + off);   off += align512(1024);
    int2*  edata  = (int2*)(ws + off);  off += align512((size_t)E * 8);
    float* A      = (float*)(ws + off); off += (size_t)N * D * 4;
    unsigned short* T = (unsigned short*)(ws + off); off += align512((size_t)N * D * 2);
    unsigned short* wt = (unsigned short*)(ws + off); off += align512((size_t)D * D * 2);
    float* konst  = (float*)(ws + off); off += align512((size_t)D * 4);

    // ---- CSR build; one memset covers cnt + sums (adjacent in ws) ----
    hipMemsetAsync(cnt, 0, align512((size_t)N * 4) + 512, stream);
    k_count<<<(E + 255) / 256, 256, 0, stream>>>(dst, cnt, E);
    k_scan1<<<NB, 256, 0, stream>>>(cnt, bsum, N);
    k_scan2<<<1, 256, 0, stream>>>(bsum, NB, rowptr + N);
    k_scan3<<<NB, 256, 0, stream>>>(cnt, bsum, rowptr, cur, dinv, N);
    k_fill<<<(E + 255) / 256, 256, 0, stream>>>(src, dst, dinv, cur, edata, E);

    // ---- encoder ----
    int tot4 = N * D4;
    k_enc<<<(tot4 + 255) / 256, 256, 0, stream>>>(x, enc_w, enc_b, A, N);

    // ---- 4 GCN layers (LN of layer L-1 folded into layer L's weights) ----
    for (int L = 0; L < 4; ++L) {
        const float* w  = (const float*)d_in[10 + 4 * L];
        const float* b  = (const float*)d_in[11 + 4 * L];
        const float* lwp = L ? (const float*)d_in[12 + 4 * (L - 1)] : nullptr;
        const float* lbp = L ? (const float*)d_in[13 + 4 * (L - 1)] : nullptr;
        k_prep<<<9, 256, 0, stream>>>(w, lwp, lbp, &sums[2 * (L ? L - 1 : 0)], wt, konst, N);
        k_mm<<<(N + 63) / 64, 256, 0, stream>>>(A, wt, konst, T, N);
        k_gather<<<(N + 15) / 16, 256, 0, stream>>>(T, edata, rowptr, dinv, b, A, &sums[2 * L], N);
    }

    // ---- fused pool + fc + pred (final LN inline) ----
    const float* lw3 = (const float*)d_in[12 + 4 * 3];
    const float* lb3 = (const float*)d_in[13 + 4 * 3];
    k_tail<<<G, 512, 0, stream>>>(A, batch, lw3, lb3, &sums[6],
                                  fc_w, fc_b, pred_w, pred_b, (float*)d_out, N);
}

// Round 12
// 533.453 us; speedup vs baseline: 4.6591x; 1.2443x over previous
//
#include <hip/hip_runtime.h>
#include <cfloat>
#include <cmath>

#define D 128
#define D4 32   // D/4 float4s per f32 row
#define LB 64   // rows per fused layer block

typedef __attribute__((ext_vector_type(8))) short short8;
typedef __attribute__((ext_vector_type(4))) float f32x4;

// ---------- helpers ----------
__device__ __forceinline__ float4 f4fma(float s, float4 a, float4 acc) {
    acc.x = fmaf(s, a.x, acc.x);
    acc.y = fmaf(s, a.y, acc.y);
    acc.z = fmaf(s, a.z, acc.z);
    acc.w = fmaf(s, a.w, acc.w);
    return acc;
}

__device__ __forceinline__ unsigned short f2bf(float x) {
    unsigned int b = __float_as_uint(x);
    unsigned int r = (b + 0x7FFFu + ((b >> 16) & 1u)) >> 16;   // RNE
    return (unsigned short)r;
}

__device__ __forceinline__ unsigned int pack2bf(float a, float b) {
    return (unsigned int)f2bf(a) | ((unsigned int)f2bf(b) << 16);
}

__device__ __forceinline__ float bf2f(unsigned short u) {
    return __uint_as_float(((unsigned int)u) << 16);
}

// accumulate 8 bf16 channels (one uint4) scaled by nrm into acc[8]
__device__ __forceinline__ void accum8(float* a, float nrm, uint4 t) {
    a[0] = fmaf(nrm, bf2f((unsigned short)(t.x & 0xFFFFu)), a[0]);
    a[1] = fmaf(nrm, bf2f((unsigned short)(t.x >> 16)), a[1]);
    a[2] = fmaf(nrm, bf2f((unsigned short)(t.y & 0xFFFFu)), a[2]);
    a[3] = fmaf(nrm, bf2f((unsigned short)(t.y >> 16)), a[3]);
    a[4] = fmaf(nrm, bf2f((unsigned short)(t.z & 0xFFFFu)), a[4]);
    a[5] = fmaf(nrm, bf2f((unsigned short)(t.z >> 16)), a[5]);
    a[6] = fmaf(nrm, bf2f((unsigned short)(t.w & 0xFFFFu)), a[6]);
    a[7] = fmaf(nrm, bf2f((unsigned short)(t.w >> 16)), a[7]);
}

// ---------- degree count (int) ----------
__global__ void k_count(const int* __restrict__ dst, int* __restrict__ cnt, int E) {
    int i = blockIdx.x * blockDim.x + threadIdx.x;
    if (i < E) atomicAdd(&cnt[dst[i]], 1);
}

// ---------- parallel scan, stage 1: per-256-chunk block sums ----------
__global__ void k_scan1(const int* __restrict__ cnt, int* __restrict__ bsum, int N) {
    __shared__ int red[256];
    int i = blockIdx.x * 256 + threadIdx.x;
    red[threadIdx.x] = (i < N) ? cnt[i] : 0;
    __syncthreads();
    for (int off = 128; off; off >>= 1) {
        if (threadIdx.x < off) red[threadIdx.x] += red[threadIdx.x + off];
        __syncthreads();
    }
    if (threadIdx.x == 0) bsum[blockIdx.x] = red[0];
}

// ---------- stage 2: single-block exclusive scan of block sums (NB<=256) ----
__global__ void k_scan2(int* __restrict__ bsum, int NB, int* __restrict__ rowptrN) {
    __shared__ int s[256];
    int t = threadIdx.x;
    int v = (t < NB) ? bsum[t] : 0;
    s[t] = v;
    __syncthreads();
    for (int off = 1; off < 256; off <<= 1) {
        int u = (t >= off) ? s[t - off] : 0;
        __syncthreads();
        s[t] += u;
        __syncthreads();
    }
    if (t < NB) bsum[t] = (t == 0) ? 0 : s[t - 1];
    if (t == 255) *rowptrN = s[255];     // rowptr[N] = E
}

// ---------- stage 3: per-chunk exclusive scan + offsets; also dinv ----------
__global__ void k_scan3(const int* __restrict__ cnt, const int* __restrict__ bsum,
                        int* __restrict__ rowptr, int* __restrict__ cur,
                        float* __restrict__ dinv, int N) {
    __shared__ int s[256];
    int i = blockIdx.x * 256 + threadIdx.x;
    int v = (i < N) ? cnt[i] : 0;
    s[threadIdx.x] = v;
    __syncthreads();
    for (int off = 1; off < 256; off <<= 1) {
        int u = (threadIdx.x >= off) ? s[threadIdx.x - off] : 0;
        __syncthreads();
        s[threadIdx.x] += u;
        __syncthreads();
    }
    if (i < N) {
        int excl = ((threadIdx.x == 0) ? 0 : s[threadIdx.x - 1]) + bsum[blockIdx.x];
        rowptr[i] = excl;
        cur[i] = excl;
        dinv[i] = 1.0f / sqrtf((float)v + 1.0f);   // +1 = self-loop
    }
}

// ---------- fill CSR edge data: (src, norm) sorted by dst ----------
__global__ void k_fill(const int* __restrict__ src, const int* __restrict__ dst,
                       const float* __restrict__ dinv, int* __restrict__ cur,
                       int2* __restrict__ edata, int E) {
    int e = blockIdx.x * blockDim.x + threadIdx.x;
    if (e >= E) return;
    int s = src[e], d = dst[e];
    int p = atomicAdd(&cur[d], 1);
    edata[p] = make_int2(s, __float_as_int(dinv[s] * dinv[d]));
}

// ---------- encoder: A0(bf16) = elu(x @ enc_w + enc_b), x:[N,3] ----------
__global__ void k_enc(const float* __restrict__ x, const float* __restrict__ w,
                      const float* __restrict__ b, unsigned short* __restrict__ h, int N) {
    int idx = blockIdx.x * blockDim.x + threadIdx.x;   // over N*D4
    if (idx >= N * D4) return;
    int n = idx >> 5, c4 = idx & 31;
    const float4* w4 = (const float4*)w;
    float4 b4 = ((const float4*)b)[c4];
    float x0 = x[n * 3 + 0], x1 = x[n * 3 + 1], x2 = x[n * 3 + 2];
    float4 v = b4;
    v = f4fma(x0, w4[0 * D4 + c4], v);
    v = f4fma(x1, w4[1 * D4 + c4], v);
    v = f4fma(x2, w4[2 * D4 + c4], v);
    v.x = v.x > 0.f ? v.x : expm1f(v.x);
    v.y = v.y > 0.f ? v.y : expm1f(v.y);
    v.z = v.z > 0.f ? v.z : expm1f(v.z);
    v.w = v.w > 0.f ? v.w : expm1f(v.w);
    ushort4 o;
    o.x = f2bf(v.x); o.y = f2bf(v.y); o.z = f2bf(v.z); o.w = f2bf(v.w);
    ((ushort4*)h)[idx] = o;
}

// ---------- per-layer LN-fold, bf16 transposed weights ----------
// wt[n][k] = bf16( sc_k * W[k][n] );  konst_j = sum_c of_c * W[c][j]  (f32)
__global__ void k_prep(const float* __restrict__ w, const float* __restrict__ lw,
                       const float* __restrict__ lb, const double* __restrict__ sums,
                       unsigned short* __restrict__ wt, float* __restrict__ konst, int N) {
    __shared__ float sc[D], of[D];
    float mu = 0.f, inv = 1.f;
    if (lw) {
        double M = (double)N * D;
        double m = sums[0] / M;
        double var = sums[1] / M - m * m;
        float sd = sqrtf(var > 0.0 ? (float)var : 0.f);
        inv = 1.f / (sd + 1e-5f);
        mu = (float)m;
    }
    for (int i = threadIdx.x; i < D; i += blockDim.x) {
        float l = lw ? lw[i] : 1.f;
        float s = inv * l;
        sc[i] = s;
        of[i] = (lw ? lb[i] : 0.f) - mu * s;
    }
    __syncthreads();
    if (blockIdx.x < 8) {
        int nl = threadIdx.x & 15;       // output col group
        int ck = threadIdx.x >> 4;       // k-chunk 0..15 (8 k each)
        int n = blockIdx.x * 16 + nl;
        unsigned int p[4];
        #pragma unroll
        for (int q = 0; q < 4; ++q) {
            int k0 = ck * 8 + 2 * q;
            float v0 = sc[k0 + 0] * w[(k0 + 0) * D + n];
            float v1 = sc[k0 + 1] * w[(k0 + 1) * D + n];
            p[q] = pack2bf(v0, v1);
        }
        uint4 u = make_uint4(p[0], p[1], p[2], p[3]);
        ((uint4*)(wt + (size_t)n * D))[ck] = u;
    } else {
        for (int j = threadIdx.x; j < D; j += blockDim.x) {
            float acc = 0.f;
            for (int c = 0; c < D; ++c) acc = fmaf(of[c], w[c * D + j], acc);
            konst[j] = acc;
        }
    }
}

// ---------- fused GCN layer ----------
// Aout = relu( (Â·Ain)·W' + rowsum(Â)·konst^T + b ), plus LN stats of Aout.
// Uses Â(LN(A)W) = (ÂA)W' + (Â1)konst^T with (Â1)_i = Σ norms + dinv_i².
// Phase 1: register gather of 64 rows (16 lanes/node, MLP-8) -> bf16 LDS tile.
// Phase 2: MFMA 16x16x32 over the LDS tile (same layout as the proven k_mm).
__launch_bounds__(256)
__global__ void k_layer(const unsigned short* __restrict__ Ain,
                        const unsigned short* __restrict__ wt,
                        const float* __restrict__ konst, const float* __restrict__ bias,
                        const int2* __restrict__ edata, const int* __restrict__ rowptr,
                        const float* __restrict__ dinv,
                        unsigned short* __restrict__ Aout,
                        double* __restrict__ sums, int N) {
    __shared__ uint4 a_lds4[1024];       // agg tile bf16 [64][128], swizzled (16 KB)
    __shared__ uint4 w_lds4[2048];       // W' bf16 [128][128], swizzled (32 KB)
    __shared__ float rs[LB];
    __shared__ float ss[4], sq[4];
    char* a_lds = (char*)a_lds4;
    char* w_lds = (char*)w_lds4;
    int row0 = blockIdx.x * LB;

    // stage W' (linear global -> swizzled LDS)
    const uint4* wg = (const uint4*)wt;
    for (int i = threadIdx.x; i < 2048; i += 256) {
        int n = i >> 4;
        int byte = (i << 4) ^ ((n & 7) << 4);
        *(uint4*)(w_lds + byte) = wg[i];
    }

    // ---- phase 1: gather 4 nodes per 16-lane group ----
    int g = threadIdx.x >> 4;
    int lane = threadIdx.x & 15;          // channels 8*lane..8*lane+7
    const uint4* T16 = (const uint4*)Ain; // row stride = 16 uint4s (256 B)
    for (int k = 0; k < 4; ++k) {
        int nl = g * 4 + k;
        int n = row0 + nl;
        if (n < N) {
            int e0 = rowptr[n], e1 = rowptr[n + 1];
            float acc[8];
            #pragma unroll
            for (int q = 0; q < 8; ++q) acc[q] = 0.f;
            float rsum = 0.f;
            int e = e0;
            for (; e + 8 <= e1; e += 8) {
                int2 ed[8]; uint4 tv[8];
                #pragma unroll
                for (int j = 0; j < 8; ++j) ed[j] = edata[e + j];
                #pragma unroll
                for (int j = 0; j < 8; ++j) tv[j] = T16[(size_t)ed[j].x * 16 + lane];
                #pragma unroll
                for (int j = 0; j < 8; ++j) {
                    float nm = __int_as_float(ed[j].y);
                    accum8(acc, nm, tv[j]);
                    rsum += nm;
                }
            }
            for (; e + 4 <= e1; e += 4) {
                int2 ed[4]; uint4 tv[4];
                #pragma unroll
                for (int j = 0; j < 4; ++j) ed[j] = edata[e + j];
                #pragma unroll
                for (int j = 0; j < 4; ++j) tv[j] = T16[(size_t)ed[j].x * 16 + lane];
                #pragma unroll
                for (int j = 0; j < 4; ++j) {
                    float nm = __int_as_float(ed[j].y);
                    accum8(acc, nm, tv[j]);
                    rsum += nm;
                }
            }
            for (; e < e1; ++e) {
                int2 d = edata[e];
                float nm = __int_as_float(d.y);
                accum8(acc, nm, T16[(size_t)d.x * 16 + lane]);
                rsum += nm;
            }
            float di = dinv[n];
            float sl = di * di;
            accum8(acc, sl, T16[(size_t)n * 16 + lane]);
            rsum += sl;
            int i = nl * 16 + lane;
            int byte = (i << 4) ^ ((nl & 7) << 4);
            *(uint4*)(a_lds + byte) = make_uint4(pack2bf(acc[0], acc[1]),
                                                 pack2bf(acc[2], acc[3]),
                                                 pack2bf(acc[4], acc[5]),
                                                 pack2bf(acc[6], acc[7]));
            if (lane == 0) rs[nl] = rsum;
        }
    }
    __syncthreads();

    // ---- phase 2: MFMA (layout proven in r11's k_mm) ----
    int wv = threadIdx.x >> 6;
    int l64 = threadIdx.x & 63;
    int lrow = l64 & 15;
    int kg = l64 >> 4;

    f32x4 acc2[8];
    #pragma unroll
    for (int ct = 0; ct < 8; ++ct) acc2[ct] = (f32x4){0.f, 0.f, 0.f, 0.f};

    #pragma unroll
    for (int ks = 0; ks < 4; ++ks) {
        int ar = wv * 16 + lrow;
        int abyte = (ar * 256 + ks * 64 + kg * 16) ^ ((ar & 7) << 4);
        short8 a = *(short8*)(a_lds + abyte);
        #pragma unroll
        for (int ct = 0; ct < 8; ++ct) {
            int wr = ct * 16 + lrow;
            int wbyte = (wr * 256 + ks * 64 + kg * 16) ^ ((wr & 7) << 4);
            short8 b = *(short8*)(w_lds + wbyte);
            acc2[ct] = __builtin_amdgcn_mfma_f32_16x16x32_bf16(a, b, acc2[ct], 0, 0, 0);
        }
    }

    // epilogue: + rs*konst + bias, relu, store bf16, LN stats
    float ls = 0.f, lq = 0.f;
    #pragma unroll
    for (int ct = 0; ct < 8; ++ct) {
        int col = ct * 16 + lrow;
        float kc = konst[col];
        float bb = bias[col];
        #pragma unroll
        for (int r = 0; r < 4; ++r) {
            int rtile = wv * 16 + kg * 4 + r;
            int row = row0 + rtile;
            if (row < N) {
                float v = acc2[ct][r] + rs[rtile] * kc + bb;
                v = fmaxf(v, 0.f);
                Aout[(size_t)row * D + col] = f2bf(v);
                ls += v;
                lq += v * v;
            }
        }
    }
    for (int off = 32; off; off >>= 1) {
        ls += __shfl_down(ls, off);
        lq += __shfl_down(lq, off);
    }
    if (l64 == 0) { ss[wv] = ls; sq[wv] = lq; }
    __syncthreads();
    if (threadIdx.x == 0) {
        float S = ss[0] + ss[1] + ss[2] + ss[3];
        float Q = sq[0] + sq[1] + sq[2] + sq[3];
        atomicAdd(&sums[0], (double)S);
        atomicAdd(&sums[1], (double)Q);
    }
}

// ---------- fused tail: pool (with final LN) + tanh-FC + pred ----------
__launch_bounds__(512)
__global__ void k_tail(const unsigned short* __restrict__ A, const int* __restrict__ batch,
                       const float* __restrict__ lw, const float* __restrict__ lb,
                       const double* __restrict__ sums,
                       const float* __restrict__ fc_w, const float* __restrict__ fc_b,
                       const float* __restrict__ pred_w, const float* __restrict__ pred_b,
                       float* __restrict__ out, int N) {
    int gi = blockIdx.x;
    int lo = 0, hi = N;
    while (lo < hi) { int mid = (lo + hi) >> 1; if (batch[mid] < gi) lo = mid + 1; else hi = mid; }
    int start = lo;
    hi = N;
    while (lo < hi) { int mid = (lo + hi) >> 1; if (batch[mid] < gi + 1) lo = mid + 1; else hi = mid; }
    int end = lo;

    int c = threadIdx.x & 127, sub = threadIdx.x >> 7;
    double M = (double)N * D;
    double m_ = sums[0] / M;
    double var = sums[1] / M - m_ * m_;
    float sd = sqrtf(var > 0.0 ? (float)var : 0.f);
    float inv = 1.f / (sd + 1e-5f);
    float s = inv * lw[c];
    float o = lb[c] - (float)m_ * s;

    float mx = -FLT_MAX;
    for (int node = start + sub; node < end; node += 4)
        mx = fmaxf(mx, fmaf(bf2f(A[(size_t)node * D + c]), s, o));

    __shared__ float red[4][128];
    __shared__ float gm[128], tr[128];
    red[sub][c] = mx;
    __syncthreads();
    if (sub == 0)
        gm[c] = fmaxf(fmaxf(red[0][c], red[1][c]), fmaxf(red[2][c], red[3][c]));
    __syncthreads();
    if (threadIdx.x < 128) {
        float acc = fc_b[c];
        for (int k = 0; k < D; ++k) acc = fmaf(gm[k], fc_w[k * D + c], acc);
        tr[c] = tanhf(acc);
    }
    __syncthreads();
    if (threadIdx.x < 10) {
        int j = threadIdx.x;
        float acc = pred_b[j];
        for (int k = 0; k < D; ++k) acc = fmaf(tr[k], pred_w[k * 10 + j], acc);
        out[gi * 10 + j] = acc;
    }
}

extern "C" void kernel_launch(void* const* d_in, const int* in_sizes, int n_in,
                              void* d_out, int out_size, void* d_ws, size_t ws_size,
                              hipStream_t stream) {
    const float* x      = (const float*)d_in[0];
    const int*   src    = (const int*)d_in[1];
    const int*   dst    = (const int*)d_in[2];
    const int*   batch  = (const int*)d_in[3];
    const float* enc_w  = (const float*)d_in[4];
    const float* enc_b  = (const float*)d_in[5];
    const float* fc_w   = (const float*)d_in[6];
    const float* fc_b   = (const float*)d_in[7];
    const float* pred_w = (const float*)d_in[8];
    const float* pred_b = (const float*)d_in[9];

    int N = in_sizes[0] / 3;
    int E = in_sizes[1];
    int G = out_size / 10;
    int NB = (N + 255) / 256;

    char* ws = (char*)d_ws;
    size_t off = 0;
    auto align512 = [](size_t v) { return (v + 511) / 512 * 512; };
    int*   cnt    = (int*)(ws + off);   off += align512((size_t)N * 4);
    double* sums  = (double*)(ws + off); off += 512;   // 4 layer slots (2 dbl each)
    float* dinv   = (float*)(ws + off); off += align512((size_t)N * 4);
    int*   rowptr = (int*)(ws + off);   off += align512(((size_t)N + 1) * 4);
    int*   cur    = (int*)(ws + off);   off += align512((size_t)N * 4);
    int*   bsum   = (int*)(ws + off);   off += align512(1024);
    int2*  edata  = (int2*)(ws + off);  off += align512((size_t)E * 8);
    unsigned short* A0 = (unsigned short*)(ws + off); off += align512((size_t)N * D * 2);
    unsigned short* A1 = (unsigned short*)(ws + off); off += align512((size_t)N * D * 2);
    unsigned short* wt = (unsigned short*)(ws + off); off += align512((size_t)D * D * 2);
    float* konst  = (float*)(ws + off); off += align512((size_t)D * 4);

    // ---- CSR build; one memset covers cnt + sums (adjacent in ws) ----
    hipMemsetAsync(cnt, 0, align512((size_t)N * 4) + 512, stream);
    k_count<<<(E + 255) / 256, 256, 0, stream>>>(dst, cnt, E);
    k_scan1<<<NB, 256, 0, stream>>>(cnt, bsum, N);
    k_scan2<<<1, 256, 0, stream>>>(bsum, NB, rowptr + N);
    k_scan3<<<NB, 256, 0, stream>>>(cnt, bsum, rowptr, cur, dinv, N);
    k_fill<<<(E + 255) / 256, 256, 0, stream>>>(src, dst, dinv, cur, edata, E);

    // ---- encoder (bf16 out) ----
    int tot4 = N * D4;
    k_enc<<<(tot4 + 255) / 256, 256, 0, stream>>>(x, enc_w, enc_b, A0, N);

    // ---- 4 fused GCN layers, double-buffered A ----
    int NBL = (N + LB - 1) / LB;
    unsigned short* Ain = A0;
    unsigned short* Aout = A1;
    for (int L = 0; L < 4; ++L) {
        const float* w  = (const float*)d_in[10 + 4 * L];
        const float* b  = (const float*)d_in[11 + 4 * L];
        const float* lwp = L ? (const float*)d_in[12 + 4 * (L - 1)] : nullptr;
        const float* lbp = L ? (const float*)d_in[13 + 4 * (L - 1)] : nullptr;
        k_prep<<<9, 256, 0, stream>>>(w, lwp, lbp, &sums[2 * (L ? L - 1 : 0)], wt, konst, N);
        k_layer<<<NBL, 256, 0, stream>>>(Ain, wt, konst, b, edata, rowptr, dinv,
                                         Aout, &sums[2 * L], N);
        unsigned short* tmp = Ain; Ain = Aout; Aout = tmp;
    }

    // ---- fused pool + fc + pred (final LN inline) ----
    const float* lw3 = (const float*)d_in[12 + 4 * 3];
    const float* lb3 = (const float*)d_in[13 + 4 * 3];
    k_tail<<<G, 512, 0, stream>>>(Ain, batch, lw3, lb3, &sums[6],
                                  fc_w, fc_b, pred_w, pred_b, (float*)d_out, N);
}